// Round 1
// baseline (1793.188 us; speedup 1.0000x reference)
//
#include <hip/hip_runtime.h>

#define DIN 55
#define HD 128

// ---------------- utility kernels ----------------
__global__ void zero_i32_kernel(int* p, int n) {
    int i = blockIdx.x * blockDim.x + threadIdx.x;
    if (i < n) p[i] = 0;
}
__global__ void zero_f32_kernel(float* p, int n) {
    int i = blockIdx.x * blockDim.x + threadIdx.x;
    if (i < n) p[i] = 0.f;
}
__global__ void copy_i32_kernel(const int* a, int* b, int n) {
    int i = blockIdx.x * blockDim.x + threadIdx.x;
    if (i < n) b[i] = a[i];
}

// ---------------- CSR construction ----------------
__global__ void hist_kernel(const int* __restrict__ dst, int* __restrict__ cnt, int E) {
    int i = blockIdx.x * blockDim.x + threadIdx.x;
    if (i < E) atomicAdd(&cnt[dst[i] + 1], 1);
}

// inclusive scan, 1024 elems per 256-thread block
__global__ __launch_bounds__(256) void scan1_kernel(int* data, int* bsums, int n) {
    __shared__ int sT[256];
    int t = threadIdx.x;
    int base = blockIdx.x * 1024 + t * 4;
    int v0 = (base + 0 < n) ? data[base + 0] : 0;
    int v1 = (base + 1 < n) ? data[base + 1] : 0;
    int v2 = (base + 2 < n) ? data[base + 2] : 0;
    int v3 = (base + 3 < n) ? data[base + 3] : 0;
    v1 += v0; v2 += v1; v3 += v2;
    sT[t] = v3;
    __syncthreads();
    for (int off = 1; off < 256; off <<= 1) {
        int x = (t >= off) ? sT[t - off] : 0;
        __syncthreads();
        sT[t] += x;
        __syncthreads();
    }
    int excl = (t == 0) ? 0 : sT[t - 1];
    if (base + 0 < n) data[base + 0] = v0 + excl;
    if (base + 1 < n) data[base + 1] = v1 + excl;
    if (base + 2 < n) data[base + 2] = v2 + excl;
    if (base + 3 < n) data[base + 3] = v3 + excl;
    if (t == 255) bsums[blockIdx.x] = sT[255];
}
__global__ void scan2_kernel(int* bsums, int nb) {
    if (threadIdx.x == 0 && blockIdx.x == 0) {
        int acc = 0;
        for (int i = 0; i < nb; i++) { int tv = bsums[i]; bsums[i] = acc; acc += tv; }
    }
}
__global__ void scan3_kernel(int* data, const int* __restrict__ bsums, int n) {
    int i = blockIdx.x * blockDim.x + threadIdx.x;
    if (i < n) data[i] += bsums[i >> 10];
}
__global__ void scatter_kernel(const int* __restrict__ src, const int* __restrict__ dst,
                               int* cursor, int* __restrict__ esrc, int E) {
    int i = blockIdx.x * blockDim.x + threadIdx.x;
    if (i < E) {
        int p = atomicAdd(&cursor[dst[i]], 1);
        esrc[p] = src[i];
    }
}

// ---------------- node projection: h = x @ W_fc + b_fc ----------------
__global__ __launch_bounds__(256) void fc_kernel(const float* __restrict__ x,
                                                 const float* __restrict__ Wfc,
                                                 const float* __restrict__ bfc,
                                                 float* __restrict__ h, int N) {
    __shared__ float sW[DIN * HD];      // 28.2 KB
    __shared__ float sx[2][DIN];
    for (int i = threadIdx.x; i < DIN * HD; i += 256) sW[i] = Wfc[i];
    int half = threadIdx.x >> 7, j = threadIdx.x & 127;
    float bj = bfc[j];
    __syncthreads();
    for (int base = blockIdx.x * 2; base < N; base += gridDim.x * 2) {
        __syncthreads();
        if (threadIdx.x < 2 * DIN) {
            int r = threadIdx.x / DIN, c = threadIdx.x % DIN;
            int nn = base + r;
            sx[r][c] = (nn < N) ? x[(size_t)nn * DIN + c] : 0.f;
        }
        __syncthreads();
        int n = base + half;
        if (n < N) {
            float acc = bj;
#pragma unroll
            for (int k = 0; k < DIN; k++) acc += sx[half][k] * sW[k * HD + j];
            h[(size_t)n * HD + j] = acc;
        }
    }
}

// ---------------- edge aggregation (CSR gather, no atomics) ----------------
__global__ __launch_bounds__(256) void agg_kernel(const float* __restrict__ h,
                                                  const int* __restrict__ off,
                                                  const int* __restrict__ esrc,
                                                  float* __restrict__ agg, int N) {
    int half = threadIdx.x >> 7, j = threadIdx.x & 127;
    int n = blockIdx.x * 2 + half;
    if (n >= N) return;
    int s0 = off[n], s1 = off[n + 1];
    float acc = 0.f;
    int t = s0;
    for (; t + 4 <= s1; t += 4) {          // 4-way unroll -> 4 independent gathers in flight
        int a = esrc[t], b = esrc[t + 1], c = esrc[t + 2], d = esrc[t + 3];
        float va = h[(size_t)a * HD + j];
        float vb = h[(size_t)b * HD + j];
        float vc = h[(size_t)c * HD + j];
        float vd = h[(size_t)d * HD + j];
        acc += va + vb + vc + vd;
    }
    for (; t < s1; t++) acc += h[(size_t)esrc[t] * HD + j];
    agg[(size_t)n * HD + j] = acc;
}

// ---------------- MLP layer: out = act(in0 (+ in1) @ W + b) ----------------
template <int RELU>
__global__ __launch_bounds__(256) void mlp_kernel(const float* __restrict__ in0,
                                                  const float* __restrict__ in1,
                                                  const float* __restrict__ W,
                                                  const float* __restrict__ b,
                                                  float* __restrict__ out, int N) {
    __shared__ float sW[HD * HD];        // 64 KB -> 2 blocks/CU
    __shared__ float sin_[2][HD];
    for (int i = threadIdx.x; i < HD * HD; i += 256) sW[i] = W[i];
    int half = threadIdx.x >> 7, j = threadIdx.x & 127;
    float bj = b[j];
    __syncthreads();
    for (int base = blockIdx.x * 2; base < N; base += gridDim.x * 2) {
        int n = base + half;
        __syncthreads();
        if (n < N) {
            float v = in0[(size_t)n * HD + j];
            if (in1) v += in1[(size_t)n * HD + j];
            sin_[half][j] = v;
        }
        __syncthreads();
        if (n < N) {
            float acc = bj;
#pragma unroll
            for (int k = 0; k < HD; k += 4) {
                float4 sv = *(const float4*)&sin_[half][k];
                acc += sv.x * sW[(k + 0) * HD + j];
                acc += sv.y * sW[(k + 1) * HD + j];
                acc += sv.z * sW[(k + 2) * HD + j];
                acc += sv.w * sW[(k + 3) * HD + j];
            }
            if (RELU) acc = fmaxf(acc, 0.f);
            out[(size_t)n * HD + j] = acc;
        }
    }
}

// ---------------- per-graph sum pool (graph_ids sorted -> run accumulate) ----------------
__global__ __launch_bounds__(128) void pool_kernel(const float* __restrict__ h,
                                                   const int* __restrict__ gid,
                                                   float* __restrict__ out, int N) {
    const int CH = 128;
    int j = threadIdx.x;
    int start = blockIdx.x * CH;
    if (start >= N) return;
    int end = min(start + CH, N);
    int cur = gid[start];
    float acc = 0.f;
    for (int n = start; n < end; n++) {
        int g = gid[n];
        if (g != cur) {
            atomicAdd(&out[(size_t)cur * HD + j], acc);
            cur = g; acc = 0.f;
        }
        acc += h[(size_t)n * HD + j];
    }
    atomicAdd(&out[(size_t)cur * HD + j], acc);
}

extern "C" void kernel_launch(void* const* d_in, const int* in_sizes, int n_in,
                              void* d_out, int out_size, void* d_ws, size_t ws_size,
                              hipStream_t stream) {
    (void)n_in; (void)ws_size;
    const float* x   = (const float*)d_in[0];
    const float* Wfc = (const float*)d_in[1];
    const float* bfc = (const float*)d_in[2];
    const float* W1  = (const float*)d_in[3];
    const float* b1  = (const float*)d_in[4];
    const float* W2  = (const float*)d_in[5];
    const float* b2  = (const float*)d_in[6];
    const int* src   = (const int*)d_in[7];
    const int* dst   = (const int*)d_in[8];
    const int* gid   = (const int*)d_in[9];

    int N = in_sizes[0] / DIN;       // 100000
    int E = in_sizes[7];             // 1600000

    // workspace layout (~110 MB)
    float* h   = (float*)d_ws;                    // N*128 f32
    float* agg = h + (size_t)N * HD;              // N*128 f32 (also holds z in-place)
    int* off    = (int*)(agg + (size_t)N * HD);   // N+1
    int* cursor = off + (N + 1);                  // N
    int* esrc   = cursor + N;                     // E
    int* bsums  = esrc + E;                       // ~128

    int nScan = N + 1;
    int nb = (nScan + 1023) / 1024;

    // CSR build: counts -> offsets -> edge lists (amortized over 3 layers)
    zero_i32_kernel<<<(nScan + 255) / 256, 256, 0, stream>>>(off, nScan);
    hist_kernel<<<(E + 255) / 256, 256, 0, stream>>>(dst, off, E);
    scan1_kernel<<<nb, 256, 0, stream>>>(off, bsums, nScan);
    scan2_kernel<<<1, 64, 0, stream>>>(bsums, nb);
    scan3_kernel<<<(nScan + 255) / 256, 256, 0, stream>>>(off, bsums, nScan);
    copy_i32_kernel<<<(N + 255) / 256, 256, 0, stream>>>(off, cursor, N);
    scatter_kernel<<<(E + 255) / 256, 256, 0, stream>>>(src, dst, cursor, esrc, E);

    // node projection
    fc_kernel<<<1024, 256, 0, stream>>>(x, Wfc, bfc, h, N);

    // 3x GINConv
    for (int l = 0; l < 3; l++) {
        agg_kernel<<<(N + 1) / 2, 256, 0, stream>>>(h, off, esrc, agg, N);
        mlp_kernel<1><<<512, 256, 0, stream>>>(h, agg, W1 + (size_t)l * HD * HD,
                                               b1 + (size_t)l * HD, agg, N);   // z -> agg (in-place)
        mlp_kernel<0><<<512, 256, 0, stream>>>(agg, nullptr, W2 + (size_t)l * HD * HD,
                                               b2 + (size_t)l * HD, h, N);     // h' -> h
    }

    // per-graph sum pooling
    zero_f32_kernel<<<(out_size + 255) / 256, 256, 0, stream>>>((float*)d_out, out_size);
    pool_kernel<<<(N + 127) / 128, 128, 0, stream>>>(h, gid, (float*)d_out, N);
}

// Round 2
// 1171.823 us; speedup vs baseline: 1.5303x; 1.5303x over previous
//
#include <hip/hip_runtime.h>

#define DIN 55
#define HD 128

// ---------------- utility kernels ----------------
__global__ void zero_i32_kernel(int* p, int n) {
    int i = blockIdx.x * blockDim.x + threadIdx.x;
    if (i < n) p[i] = 0;
}
__global__ void zero_f32_kernel(float* p, int n) {
    int i = blockIdx.x * blockDim.x + threadIdx.x;
    if (i < n) p[i] = 0.f;
}
__global__ void copy_i32_kernel(const int* a, int* b, int n) {
    int i = blockIdx.x * blockDim.x + threadIdx.x;
    if (i < n) b[i] = a[i];
}

// ---------------- CSR construction ----------------
__global__ void hist_kernel(const int* __restrict__ dst, int* __restrict__ cnt, int E) {
    int i = blockIdx.x * blockDim.x + threadIdx.x;
    if (i < E) atomicAdd(&cnt[dst[i] + 1], 1);
}

__global__ __launch_bounds__(256) void scan1_kernel(int* data, int* bsums, int n) {
    __shared__ int sT[256];
    int t = threadIdx.x;
    int base = blockIdx.x * 1024 + t * 4;
    int v0 = (base + 0 < n) ? data[base + 0] : 0;
    int v1 = (base + 1 < n) ? data[base + 1] : 0;
    int v2 = (base + 2 < n) ? data[base + 2] : 0;
    int v3 = (base + 3 < n) ? data[base + 3] : 0;
    v1 += v0; v2 += v1; v3 += v2;
    sT[t] = v3;
    __syncthreads();
    for (int off = 1; off < 256; off <<= 1) {
        int x = (t >= off) ? sT[t - off] : 0;
        __syncthreads();
        sT[t] += x;
        __syncthreads();
    }
    int excl = (t == 0) ? 0 : sT[t - 1];
    if (base + 0 < n) data[base + 0] = v0 + excl;
    if (base + 1 < n) data[base + 1] = v1 + excl;
    if (base + 2 < n) data[base + 2] = v2 + excl;
    if (base + 3 < n) data[base + 3] = v3 + excl;
    if (t == 255) bsums[blockIdx.x] = sT[255];
}
__global__ void scan2_kernel(int* bsums, int nb) {
    if (threadIdx.x == 0 && blockIdx.x == 0) {
        int acc = 0;
        for (int i = 0; i < nb; i++) { int tv = bsums[i]; bsums[i] = acc; acc += tv; }
    }
}
__global__ void scan3_kernel(int* data, const int* __restrict__ bsums, int n) {
    int i = blockIdx.x * blockDim.x + threadIdx.x;
    if (i < n) data[i] += bsums[i >> 10];
}
__global__ void scatter_kernel(const int* __restrict__ src, const int* __restrict__ dst,
                               int* cursor, int* __restrict__ esrc, int E) {
    int i = blockIdx.x * blockDim.x + threadIdx.x;
    if (i < E) {
        int p = atomicAdd(&cursor[dst[i]], 1);
        esrc[p] = src[i];
    }
}

// helper: select float4 component by compile-time-constant index
__device__ __forceinline__ float f4c(const float4& v, int kk) {
    return kk == 0 ? v.x : kk == 1 ? v.y : kk == 2 ? v.z : v.w;
}

// ---------------- node projection: h = x @ W_fc + b_fc ----------------
// Register-tiled: 512 threads, 128-node tile, each thread 4 nodes x 8 cols.
__global__ __launch_bounds__(512, 2) void fc_kernel(const float* __restrict__ x,
                                                    const float* __restrict__ Wfc,
                                                    const float* __restrict__ bfc,
                                                    float* __restrict__ h,
                                                    int N, int nTiles) {
    __shared__ float sW[DIN * HD];       // 27.5 KB, [k][j]
    __shared__ float sX[128 * 56];       // 28.7 KB, [n][k] pad 56
    for (int i = threadIdx.x; i < DIN * HD / 4; i += 512)
        ((float4*)sW)[i] = ((const float4*)Wfc)[i];
    const int c = threadIdx.x & 15;      // j0 = 8c
    const int r = threadIdx.x >> 4;      // n0 = 4r
    float4 bb0 = ((const float4*)bfc)[2 * c];
    float4 bb1 = ((const float4*)bfc)[2 * c + 1];

    for (int tile = blockIdx.x; tile < nTiles; tile += gridDim.x) {
        int base = tile * 128;
        int limit = min(128, N - base) * DIN;
        __syncthreads();
        for (int i = threadIdx.x; i < 128 * DIN; i += 512) {
            float v = (i < limit) ? x[(size_t)base * DIN + i] : 0.f;
            sX[(i / DIN) * 56 + (i % DIN)] = v;
        }
        __syncthreads();

        float acc[4][8];
#pragma unroll
        for (int ii = 0; ii < 4; ii++) {
            acc[ii][0] = bb0.x; acc[ii][1] = bb0.y; acc[ii][2] = bb0.z; acc[ii][3] = bb0.w;
            acc[ii][4] = bb1.x; acc[ii][5] = bb1.y; acc[ii][6] = bb1.z; acc[ii][7] = bb1.w;
        }
        const int n0 = r * 4;
#pragma unroll 5
        for (int k = 0; k < DIN; k++) {
            float4 w0 = *(const float4*)&sW[k * HD + c * 8];
            float4 w1 = *(const float4*)&sW[k * HD + c * 8 + 4];
            float a0 = sX[(n0 + 0) * 56 + k];
            float a1 = sX[(n0 + 1) * 56 + k];
            float a2 = sX[(n0 + 2) * 56 + k];
            float a3 = sX[(n0 + 3) * 56 + k];
            float av[4] = {a0, a1, a2, a3};
#pragma unroll
            for (int ii = 0; ii < 4; ii++) {
                acc[ii][0] += av[ii] * w0.x; acc[ii][1] += av[ii] * w0.y;
                acc[ii][2] += av[ii] * w0.z; acc[ii][3] += av[ii] * w0.w;
                acc[ii][4] += av[ii] * w1.x; acc[ii][5] += av[ii] * w1.y;
                acc[ii][6] += av[ii] * w1.z; acc[ii][7] += av[ii] * w1.w;
            }
        }
        int nvalid = N - base;
#pragma unroll
        for (int ii = 0; ii < 4; ii++) {
            if (n0 + ii < nvalid) {
                float* o = h + (size_t)(base + n0 + ii) * HD + c * 8;
                *(float4*)o = make_float4(acc[ii][0], acc[ii][1], acc[ii][2], acc[ii][3]);
                *(float4*)(o + 4) = make_float4(acc[ii][4], acc[ii][5], acc[ii][6], acc[ii][7]);
            }
        }
    }
}

// ---------------- edge aggregation (CSR gather, no atomics) ----------------
__global__ __launch_bounds__(256) void agg_kernel(const float* __restrict__ h,
                                                  const int* __restrict__ off,
                                                  const int* __restrict__ esrc,
                                                  float* __restrict__ agg, int N) {
    int half = threadIdx.x >> 7, j = threadIdx.x & 127;
    int n = blockIdx.x * 2 + half;
    if (n >= N) return;
    int s0 = off[n], s1 = off[n + 1];
    float acc = 0.f;
    int t = s0;
    for (; t + 4 <= s1; t += 4) {
        int a = esrc[t], b = esrc[t + 1], c = esrc[t + 2], d = esrc[t + 3];
        float va = h[(size_t)a * HD + j];
        float vb = h[(size_t)b * HD + j];
        float vc = h[(size_t)c * HD + j];
        float vd = h[(size_t)d * HD + j];
        acc += va + vb + vc + vd;
    }
    for (; t < s1; t++) acc += h[(size_t)esrc[t] * HD + j];
    agg[(size_t)n * HD + j] = acc;
}

// ---------------- MLP layer: out = act((in0 (+ in1)) @ W + b) ----------------
// 512 threads, persistent, 128-node tile; thread computes 4 nodes x 8 cols.
// LDS: W 64KB + X-tile 67.5KB = 130KB -> 1 block/CU, 8 waves.
template <int RELU>
__global__ __launch_bounds__(512, 2) void mlp_kernel(const float* __restrict__ in0,
                                                     const float* __restrict__ in1,
                                                     const float* __restrict__ W,
                                                     const float* __restrict__ b,
                                                     float* __restrict__ out,
                                                     int N, int nTiles) {
    __shared__ float sW[HD * HD];        // 64 KB, [k][j]
    __shared__ float sX[128 * 132];      // 67.6 KB, [n][k] padded to 132
    for (int i = threadIdx.x; i < HD * HD / 4; i += 512)
        ((float4*)sW)[i] = ((const float4*)W)[i];
    const int c = threadIdx.x & 15;      // col group: j0 = 8c
    const int r = threadIdx.x >> 4;     // 0..31 : n0 = 4r
    float4 bb0 = ((const float4*)b)[2 * c];
    float4 bb1 = ((const float4*)b)[2 * c + 1];

    for (int tile = blockIdx.x; tile < nTiles; tile += gridDim.x) {
        int base = tile * 128;
        const float4* p0 = (const float4*)(in0 + (size_t)base * HD);
        const float4* p1 = in1 ? (const float4*)(in1 + (size_t)base * HD) : nullptr;
        int limit4 = min(128, N - base) * 32;
        __syncthreads();                  // all reads of previous sX done
        for (int i = threadIdx.x; i < 128 * 32; i += 512) {
            float4 v = make_float4(0.f, 0.f, 0.f, 0.f);
            if (i < limit4) {
                v = p0[i];
                if (p1) {
                    float4 u = p1[i];
                    v.x += u.x; v.y += u.y; v.z += u.z; v.w += u.w;
                }
            }
            int n = i >> 5, k4 = i & 31;
            *(float4*)&sX[n * 132 + k4 * 4] = v;
        }
        __syncthreads();

        float acc[4][8];
#pragma unroll
        for (int ii = 0; ii < 4; ii++) {
            acc[ii][0] = bb0.x; acc[ii][1] = bb0.y; acc[ii][2] = bb0.z; acc[ii][3] = bb0.w;
            acc[ii][4] = bb1.x; acc[ii][5] = bb1.y; acc[ii][6] = bb1.z; acc[ii][7] = bb1.w;
        }
        const int n0 = r * 4;
#pragma unroll 4
        for (int k = 0; k < HD; k += 4) {
            float4 a0 = *(const float4*)&sX[(n0 + 0) * 132 + k];
            float4 a1 = *(const float4*)&sX[(n0 + 1) * 132 + k];
            float4 a2 = *(const float4*)&sX[(n0 + 2) * 132 + k];
            float4 a3 = *(const float4*)&sX[(n0 + 3) * 132 + k];
#pragma unroll
            for (int kk = 0; kk < 4; kk++) {
                float4 w0 = *(const float4*)&sW[(k + kk) * HD + c * 8];
                float4 w1 = *(const float4*)&sW[(k + kk) * HD + c * 8 + 4];
                float av[4] = {f4c(a0, kk), f4c(a1, kk), f4c(a2, kk), f4c(a3, kk)};
#pragma unroll
                for (int ii = 0; ii < 4; ii++) {
                    acc[ii][0] += av[ii] * w0.x; acc[ii][1] += av[ii] * w0.y;
                    acc[ii][2] += av[ii] * w0.z; acc[ii][3] += av[ii] * w0.w;
                    acc[ii][4] += av[ii] * w1.x; acc[ii][5] += av[ii] * w1.y;
                    acc[ii][6] += av[ii] * w1.z; acc[ii][7] += av[ii] * w1.w;
                }
            }
        }
        int nvalid = N - base;
#pragma unroll
        for (int ii = 0; ii < 4; ii++) {
            if (n0 + ii < nvalid) {
                float v0x = acc[ii][0], v0y = acc[ii][1], v0z = acc[ii][2], v0w = acc[ii][3];
                float v1x = acc[ii][4], v1y = acc[ii][5], v1z = acc[ii][6], v1w = acc[ii][7];
                if (RELU) {
                    v0x = fmaxf(v0x, 0.f); v0y = fmaxf(v0y, 0.f);
                    v0z = fmaxf(v0z, 0.f); v0w = fmaxf(v0w, 0.f);
                    v1x = fmaxf(v1x, 0.f); v1y = fmaxf(v1y, 0.f);
                    v1z = fmaxf(v1z, 0.f); v1w = fmaxf(v1w, 0.f);
                }
                float* o = out + (size_t)(base + n0 + ii) * HD + c * 8;
                *(float4*)o = make_float4(v0x, v0y, v0z, v0w);
                *(float4*)(o + 4) = make_float4(v1x, v1y, v1z, v1w);
            }
        }
    }
}

// ---------------- per-graph sum pool (graph_ids sorted -> run accumulate) ----------------
__global__ __launch_bounds__(128) void pool_kernel(const float* __restrict__ h,
                                                   const int* __restrict__ gid,
                                                   float* __restrict__ out, int N) {
    const int CH = 128;
    int j = threadIdx.x;
    int start = blockIdx.x * CH;
    if (start >= N) return;
    int end = min(start + CH, N);
    int cur = gid[start];
    float acc = 0.f;
    for (int n = start; n < end; n++) {
        int g = gid[n];
        if (g != cur) {
            atomicAdd(&out[(size_t)cur * HD + j], acc);
            cur = g; acc = 0.f;
        }
        acc += h[(size_t)n * HD + j];
    }
    atomicAdd(&out[(size_t)cur * HD + j], acc);
}

extern "C" void kernel_launch(void* const* d_in, const int* in_sizes, int n_in,
                              void* d_out, int out_size, void* d_ws, size_t ws_size,
                              hipStream_t stream) {
    (void)n_in; (void)ws_size;
    const float* x   = (const float*)d_in[0];
    const float* Wfc = (const float*)d_in[1];
    const float* bfc = (const float*)d_in[2];
    const float* W1  = (const float*)d_in[3];
    const float* b1  = (const float*)d_in[4];
    const float* W2  = (const float*)d_in[5];
    const float* b2  = (const float*)d_in[6];
    const int* src   = (const int*)d_in[7];
    const int* dst   = (const int*)d_in[8];
    const int* gid   = (const int*)d_in[9];

    int N = in_sizes[0] / DIN;       // 100000
    int E = in_sizes[7];             // 1600000
    int nTiles = (N + 127) / 128;

    // workspace layout (~110 MB)
    float* h   = (float*)d_ws;                    // N*128 f32
    float* agg = h + (size_t)N * HD;              // N*128 f32 (also holds z in-place)
    int* off    = (int*)(agg + (size_t)N * HD);   // N+1
    int* cursor = off + (N + 1);                  // N
    int* esrc   = cursor + N;                     // E
    int* bsums  = esrc + E;                       // ~128

    int nScan = N + 1;
    int nb = (nScan + 1023) / 1024;

    // CSR build
    zero_i32_kernel<<<(nScan + 255) / 256, 256, 0, stream>>>(off, nScan);
    hist_kernel<<<(E + 255) / 256, 256, 0, stream>>>(dst, off, E);
    scan1_kernel<<<nb, 256, 0, stream>>>(off, bsums, nScan);
    scan2_kernel<<<1, 64, 0, stream>>>(bsums, nb);
    scan3_kernel<<<(nScan + 255) / 256, 256, 0, stream>>>(off, bsums, nScan);
    copy_i32_kernel<<<(N + 255) / 256, 256, 0, stream>>>(off, cursor, N);
    scatter_kernel<<<(E + 255) / 256, 256, 0, stream>>>(src, dst, cursor, esrc, E);

    // node projection
    fc_kernel<<<512, 512, 0, stream>>>(x, Wfc, bfc, h, N, nTiles);

    // 3x GINConv
    for (int l = 0; l < 3; l++) {
        agg_kernel<<<(N + 1) / 2, 256, 0, stream>>>(h, off, esrc, agg, N);
        mlp_kernel<1><<<256, 512, 0, stream>>>(h, agg, W1 + (size_t)l * HD * HD,
                                               b1 + (size_t)l * HD, agg, N, nTiles);
        mlp_kernel<0><<<256, 512, 0, stream>>>(agg, nullptr, W2 + (size_t)l * HD * HD,
                                               b2 + (size_t)l * HD, h, N, nTiles);
    }

    // per-graph sum pooling
    zero_f32_kernel<<<(out_size + 255) / 256, 256, 0, stream>>>((float*)d_out, out_size);
    pool_kernel<<<(N + 127) / 128, 128, 0, stream>>>(h, gid, (float*)d_out, N);
}

// Round 3
// 1150.262 us; speedup vs baseline: 1.5589x; 1.0187x over previous
//
#include <hip/hip_runtime.h>

#define DIN 55
#define HD 128

typedef unsigned short u16;
typedef unsigned int u32;
typedef short short8 __attribute__((ext_vector_type(8)));
typedef float f32x4 __attribute__((ext_vector_type(4)));

// ---- bf16 helpers ----
__device__ __forceinline__ u16 f2bf(float f) {
    u32 u = __float_as_uint(f);
    u32 r = (u + 0x7FFFu + ((u >> 16) & 1u)) >> 16;
    return (u16)r;
}
__device__ __forceinline__ float bfLo(u32 u) { return __uint_as_float(u << 16); }
__device__ __forceinline__ float bfHi(u32 u) { return __uint_as_float(u & 0xFFFF0000u); }

// ---------------- utility kernels ----------------
__global__ void zero_i32_kernel(int* p, int n) {
    int i = blockIdx.x * blockDim.x + threadIdx.x;
    if (i < n) p[i] = 0;
}
__global__ void zero_f32_kernel(float* p, int n) {
    int i = blockIdx.x * blockDim.x + threadIdx.x;
    if (i < n) p[i] = 0.f;
}
__global__ void copy_i32_kernel(const int* a, int* b, int n) {
    int i = blockIdx.x * blockDim.x + threadIdx.x;
    if (i < n) b[i] = a[i];
}

// ---------------- CSR construction (bucketed) ----------------
// per-node histogram (counts at off[n+1])
__global__ void hist_kernel(const int* __restrict__ dst, int* __restrict__ cnt, int E) {
    int i = blockIdx.x * blockDim.x + threadIdx.x;
    if (i < E) atomicAdd(&cnt[dst[i] + 1], 1);
}

__global__ __launch_bounds__(256) void scan1_kernel(int* data, int* bsums, int n) {
    __shared__ int sT[256];
    int t = threadIdx.x;
    int base = blockIdx.x * 1024 + t * 4;
    int v0 = (base + 0 < n) ? data[base + 0] : 0;
    int v1 = (base + 1 < n) ? data[base + 1] : 0;
    int v2 = (base + 2 < n) ? data[base + 2] : 0;
    int v3 = (base + 3 < n) ? data[base + 3] : 0;
    v1 += v0; v2 += v1; v3 += v2;
    sT[t] = v3;
    __syncthreads();
    for (int off = 1; off < 256; off <<= 1) {
        int x = (t >= off) ? sT[t - off] : 0;
        __syncthreads();
        sT[t] += x;
        __syncthreads();
    }
    int excl = (t == 0) ? 0 : sT[t - 1];
    if (base + 0 < n) data[base + 0] = v0 + excl;
    if (base + 1 < n) data[base + 1] = v1 + excl;
    if (base + 2 < n) data[base + 2] = v2 + excl;
    if (base + 3 < n) data[base + 3] = v3 + excl;
    if (t == 255) bsums[blockIdx.x] = sT[255];
}
__global__ void scan2_kernel(int* bsums, int nb) {
    if (threadIdx.x == 0 && blockIdx.x == 0) {
        int acc = 0;
        for (int i = 0; i < nb; i++) { int tv = bsums[i]; bsums[i] = acc; acc += tv; }
    }
}
__global__ void scan3_kernel(int* data, const int* __restrict__ bsums, int n) {
    int i = blockIdx.x * blockDim.x + threadIdx.x;
    if (i < n) data[i] += bsums[i >> 10];
}

// bucket histogram: bucket = dst >> 8 (256-node windows), LDS-accumulated
__global__ __launch_bounds__(256) void bhist_kernel(const int* __restrict__ dst,
                                                    int* __restrict__ bcnt, int E) {
    __shared__ int hh[512];
    int t = threadIdx.x;
    for (int i = t; i < 512; i += 256) hh[i] = 0;
    __syncthreads();
    int base = blockIdx.x * 4096;
    int end = min(base + 4096, E);
    for (int i = base + t; i < end; i += 256) atomicAdd(&hh[dst[i] >> 8], 1);
    __syncthreads();
    for (int i = t; i < 512; i += 256)
        if (hh[i]) atomicAdd(&bcnt[i], hh[i]);
}

// scan bucket counts -> boff (exclusive, B+1) and bcur (= boff[b])
__global__ __launch_bounds__(512) void bscan_kernel(const int* __restrict__ bcnt,
                                                    int* __restrict__ boff,
                                                    int* __restrict__ bcur, int B) {
    __shared__ int s[512];
    int t = threadIdx.x;
    int v = (t < B) ? bcnt[t] : 0;
    s[t] = v;
    __syncthreads();
    for (int o = 1; o < 512; o <<= 1) {
        int x = (t >= o) ? s[t - o] : 0;
        __syncthreads();
        s[t] += x;
        __syncthreads();
    }
    if (t < B) {
        boff[t + 1] = s[t];
        bcur[t] = s[t] - v;
        if (t == 0) boff[0] = 0;
    }
}

// fill buckets with (src,dst) pairs; writes within a bucket fill near-sequentially
__global__ void bfill_kernel(const int* __restrict__ src, const int* __restrict__ dst,
                             int* bcur, uint2* __restrict__ bpairs, int E) {
    int i = blockIdx.x * blockDim.x + threadIdx.x;
    if (i < E) {
        int d = dst[i];
        int p = atomicAdd(&bcur[d >> 8], 1);
        bpairs[p] = make_uint2((u32)src[i], (u32)d);
    }
}

// per-bucket final scatter: target window is ~64KB -> L2-resident
__global__ __launch_bounds__(256) void bscatter_kernel(const uint2* __restrict__ bpairs,
                                                       const int* __restrict__ boff,
                                                       int* cursor, int* __restrict__ esrc) {
    int b = blockIdx.x;
    int lo = boff[b], hi = boff[b + 1];
    for (int i = lo + threadIdx.x; i < hi; i += 256) {
        uint2 u = bpairs[i];
        int p = atomicAdd(&cursor[u.y], 1);
        esrc[p] = (int)u.x;
    }
}

// ---------------- node projection: h = x @ W_fc + b_fc  (fp32 math, bf16 out) ----------------
__global__ __launch_bounds__(512, 2) void fc_kernel(const float* __restrict__ x,
                                                    const float* __restrict__ Wfc,
                                                    const float* __restrict__ bfc,
                                                    u16* __restrict__ h,
                                                    int N, int nTiles) {
    __shared__ float sW[DIN * HD];
    __shared__ float sX[128 * 56];
    for (int i = threadIdx.x; i < DIN * HD / 4; i += 512)
        ((float4*)sW)[i] = ((const float4*)Wfc)[i];
    const int c = threadIdx.x & 15;
    const int r = threadIdx.x >> 4;
    float4 bb0 = ((const float4*)bfc)[2 * c];
    float4 bb1 = ((const float4*)bfc)[2 * c + 1];

    for (int tile = blockIdx.x; tile < nTiles; tile += gridDim.x) {
        int base = tile * 128;
        int limit = min(128, N - base) * DIN;
        __syncthreads();
        for (int i = threadIdx.x; i < 128 * DIN; i += 512) {
            float v = (i < limit) ? x[(size_t)base * DIN + i] : 0.f;
            sX[(i / DIN) * 56 + (i % DIN)] = v;
        }
        __syncthreads();

        float acc[4][8];
#pragma unroll
        for (int ii = 0; ii < 4; ii++) {
            acc[ii][0] = bb0.x; acc[ii][1] = bb0.y; acc[ii][2] = bb0.z; acc[ii][3] = bb0.w;
            acc[ii][4] = bb1.x; acc[ii][5] = bb1.y; acc[ii][6] = bb1.z; acc[ii][7] = bb1.w;
        }
        const int n0 = r * 4;
#pragma unroll 5
        for (int k = 0; k < DIN; k++) {
            float4 w0 = *(const float4*)&sW[k * HD + c * 8];
            float4 w1 = *(const float4*)&sW[k * HD + c * 8 + 4];
            float av[4] = {sX[(n0 + 0) * 56 + k], sX[(n0 + 1) * 56 + k],
                           sX[(n0 + 2) * 56 + k], sX[(n0 + 3) * 56 + k]};
#pragma unroll
            for (int ii = 0; ii < 4; ii++) {
                acc[ii][0] += av[ii] * w0.x; acc[ii][1] += av[ii] * w0.y;
                acc[ii][2] += av[ii] * w0.z; acc[ii][3] += av[ii] * w0.w;
                acc[ii][4] += av[ii] * w1.x; acc[ii][5] += av[ii] * w1.y;
                acc[ii][6] += av[ii] * w1.z; acc[ii][7] += av[ii] * w1.w;
            }
        }
        int nvalid = N - base;
#pragma unroll
        for (int ii = 0; ii < 4; ii++) {
            if (n0 + ii < nvalid) {
                u32 p0 = (u32)f2bf(acc[ii][0]) | ((u32)f2bf(acc[ii][1]) << 16);
                u32 p1 = (u32)f2bf(acc[ii][2]) | ((u32)f2bf(acc[ii][3]) << 16);
                u32 p2 = (u32)f2bf(acc[ii][4]) | ((u32)f2bf(acc[ii][5]) << 16);
                u32 p3 = (u32)f2bf(acc[ii][6]) | ((u32)f2bf(acc[ii][7]) << 16);
                *(uint4*)&h[(size_t)(base + n0 + ii) * HD + c * 8] = make_uint4(p0, p1, p2, p3);
            }
        }
    }
}

// ---------------- edge aggregation: z[n] = h[n] + sum_{e} h[esrc[e]]  (bf16) ----------------
// one wave per node; lane: edge-parity = lane>>5, feature quad q = lane&31 (8B per lane)
__global__ __launch_bounds__(256) void agg_kernel(const u16* __restrict__ h,
                                                  const int* __restrict__ off,
                                                  const int* __restrict__ esrc,
                                                  u16* __restrict__ z, int N) {
    int w = threadIdx.x >> 6, lane = threadIdx.x & 63;
    int n = blockIdx.x * 4 + w;
    if (n >= N) return;
    int s0 = off[n], s1 = off[n + 1];
    int epar = lane >> 5, q = lane & 31;
    float a0 = 0.f, a1 = 0.f, a2 = 0.f, a3 = 0.f;
    int t = s0;
    for (; t + 8 <= s1; t += 8) {
        int e0 = esrc[t + 0 + epar], e1 = esrc[t + 2 + epar];
        int e2 = esrc[t + 4 + epar], e3 = esrc[t + 6 + epar];
        uint2 v0 = *(const uint2*)&h[(size_t)e0 * HD + q * 4];
        uint2 v1 = *(const uint2*)&h[(size_t)e1 * HD + q * 4];
        uint2 v2 = *(const uint2*)&h[(size_t)e2 * HD + q * 4];
        uint2 v3 = *(const uint2*)&h[(size_t)e3 * HD + q * 4];
        a0 += bfLo(v0.x) + bfLo(v1.x) + bfLo(v2.x) + bfLo(v3.x);
        a1 += bfHi(v0.x) + bfHi(v1.x) + bfHi(v2.x) + bfHi(v3.x);
        a2 += bfLo(v0.y) + bfLo(v1.y) + bfLo(v2.y) + bfLo(v3.y);
        a3 += bfHi(v0.y) + bfHi(v1.y) + bfHi(v2.y) + bfHi(v3.y);
    }
    for (; t + 2 <= s1; t += 2) {
        int e0 = esrc[t + epar];
        uint2 v0 = *(const uint2*)&h[(size_t)e0 * HD + q * 4];
        a0 += bfLo(v0.x); a1 += bfHi(v0.x); a2 += bfLo(v0.y); a3 += bfHi(v0.y);
    }
    if (t < s1 && epar == 0) {
        int e0 = esrc[t];
        uint2 v0 = *(const uint2*)&h[(size_t)e0 * HD + q * 4];
        a0 += bfLo(v0.x); a1 += bfHi(v0.x); a2 += bfLo(v0.y); a3 += bfHi(v0.y);
    }
    a0 += __shfl_down(a0, 32);
    a1 += __shfl_down(a1, 32);
    a2 += __shfl_down(a2, 32);
    a3 += __shfl_down(a3, 32);
    if (epar == 0) {
        uint2 sv = *(const uint2*)&h[(size_t)n * HD + q * 4];
        a0 += bfLo(sv.x); a1 += bfHi(sv.x); a2 += bfLo(sv.y); a3 += bfHi(sv.y);
        u32 p0 = (u32)f2bf(a0) | ((u32)f2bf(a1) << 16);
        u32 p1 = (u32)f2bf(a2) | ((u32)f2bf(a3) << 16);
        *(uint2*)&z[(size_t)n * HD + q * 4] = make_uint2(p0, p1);
    }
}

// ---------------- MFMA MLP: out = act(in @ W + b), in/out bf16, W/b fp32 ----------------
// 512 threads = 8 waves. Tile 128 nodes x 128 cols, K=128, mfma_f32_16x16x32_bf16.
// Wave w: rows (w&3)*32 .. +32 (2 row-tiles), cols (w>>2)*64 .. +64 (4 col-tiles).
// Fragment-ordered LDS with slot = lane ^ (kc<<1) swizzle (conflict-free reads).
__global__ __launch_bounds__(512, 4) void mlp_mfma_kernel(const u16* __restrict__ in,
                                                          const float* __restrict__ W,
                                                          const float* __restrict__ b,
                                                          u16* __restrict__ out,
                                                          int N, int nTiles, int relu) {
    __shared__ u16 sB[8 * 4 * 64 * 8];   // 32 KB: [ct][kc][slot][8]
    __shared__ u16 sA[16896];            // 33 KB: frags [rt][kc][slot][8] (16384) / W-row scratch 128x132

    const int t = threadIdx.x;
    // --- stage W (fp32 -> bf16) into row scratch, stride 132 ---
    for (int c = t; c < 128 * 32; c += 512) {
        int k = c >> 5, j4 = c & 31;
        float4 wv = ((const float4*)W)[c];
        u32 p0 = (u32)f2bf(wv.x) | ((u32)f2bf(wv.y) << 16);
        u32 p1 = (u32)f2bf(wv.z) | ((u32)f2bf(wv.w) << 16);
        *(uint2*)&sA[k * 132 + j4 * 4] = make_uint2(p0, p1);
    }
    __syncthreads();
    // --- build B fragments: lane holds W[k0..k0+7][j], j = ct*16 + (L&15), k0 = kc*32 + (L>>4)*8 ---
    for (int e = t; e < 2048; e += 512) {
        int L = e & 63, g = e >> 6;
        int ct = g >> 2, kc = g & 3;
        int j = ct * 16 + (L & 15);
        int k0 = kc * 32 + ((L >> 4) << 3);
        short8 sv;
#pragma unroll
        for (int i = 0; i < 8; i++) sv[i] = (short)sA[(k0 + i) * 132 + j];
        int slot = L ^ (kc << 1);
        *(short8*)&sB[(((ct << 2) + kc) << 6 | slot) * 8] = sv;
    }

    const int w = t >> 6, lane = t & 63;
    const int rbase = (w & 3) << 5;      // 0,32,64,96
    const int cbase = (w >> 2) << 6;     // 0 or 64
    float bias[4];
#pragma unroll
    for (int ct = 0; ct < 4; ct++) bias[ct] = b[cbase + ct * 16 + (lane & 15)];

    for (int tile = blockIdx.x; tile < nTiles; tile += gridDim.x) {
        int base = tile * 128;
        int nvalid = N - base;
        __syncthreads();   // previous tile's reads done (also covers sB build on first iter)
        // --- stage input tile into A fragments (coalesced global read, swizzled LDS write) ---
        int limit = min(128, nvalid) * 16;
        for (int c = t; c < 2048; c += 512) {
            int n = c >> 4, k8 = c & 15;
            uint4 raw = make_uint4(0, 0, 0, 0);
            if (c < limit)
                raw = *(const uint4*)&in[((size_t)(base + n)) * HD + k8 * 8];
            int rt = n >> 4, kc = k8 >> 2;
            int L = ((k8 & 3) << 4) | (n & 15);
            int slot = L ^ (kc << 1);
            *(uint4*)&sA[(((rt << 2) + kc) << 6 | slot) * 8] = raw;
        }
        __syncthreads();

        // --- compute ---
        short8 af[2][4];
#pragma unroll
        for (int rt = 0; rt < 2; rt++) {
            int rtg = (rbase >> 4) + rt;
#pragma unroll
            for (int kc = 0; kc < 4; kc++)
                af[rt][kc] = *(const short8*)&sA[(((rtg << 2) + kc) << 6 | (lane ^ (kc << 1))) * 8];
        }
        f32x4 acc[2][4];
#pragma unroll
        for (int rt = 0; rt < 2; rt++)
#pragma unroll
            for (int ct = 0; ct < 4; ct++) {
                acc[rt][ct][0] = bias[ct]; acc[rt][ct][1] = bias[ct];
                acc[rt][ct][2] = bias[ct]; acc[rt][ct][3] = bias[ct];
            }
#pragma unroll
        for (int ct = 0; ct < 4; ct++) {
            int ctg = (cbase >> 4) + ct;
#pragma unroll
            for (int kc = 0; kc < 4; kc++) {
                short8 bf = *(const short8*)&sB[(((ctg << 2) + kc) << 6 | (lane ^ (kc << 1))) * 8];
                acc[0][ct] = __builtin_amdgcn_mfma_f32_16x16x32_bf16(af[0][kc], bf, acc[0][ct], 0, 0, 0);
                acc[1][ct] = __builtin_amdgcn_mfma_f32_16x16x32_bf16(af[1][kc], bf, acc[1][ct], 0, 0, 0);
            }
        }
        // --- epilogue: C/D layout col=lane&15, row=(lane>>4)*4+reg ---
#pragma unroll
        for (int rt = 0; rt < 2; rt++) {
            int rowb = rbase + rt * 16 + ((lane >> 4) << 2);
#pragma unroll
            for (int ct = 0; ct < 4; ct++) {
                int col = cbase + ct * 16 + (lane & 15);
#pragma unroll
                for (int reg = 0; reg < 4; reg++) {
                    int row = rowb + reg;
                    if (row < nvalid) {
                        float v = acc[rt][ct][reg];
                        if (relu) v = fmaxf(v, 0.f);
                        out[(size_t)(base + row) * HD + col] = f2bf(v);
                    }
                }
            }
        }
    }
}

// ---------------- per-graph sum pool (bf16 in, fp32 atomics out) ----------------
__global__ __launch_bounds__(64) void pool_kernel(const u16* __restrict__ h,
                                                  const int* __restrict__ gid,
                                                  float* __restrict__ out, int N) {
    int j = threadIdx.x;                 // 0..63, features 2j, 2j+1
    int start = blockIdx.x * 128;
    if (start >= N) return;
    int end = min(start + 128, N);
    int cur = gid[start];
    float x0 = 0.f, x1 = 0.f;
    for (int n = start; n < end; n++) {
        int g = gid[n];
        if (g != cur) {
            atomicAdd(&out[(size_t)cur * HD + 2 * j], x0);
            atomicAdd(&out[(size_t)cur * HD + 2 * j + 1], x1);
            cur = g; x0 = 0.f; x1 = 0.f;
        }
        u32 v = *(const u32*)&h[(size_t)n * HD + j * 2];
        x0 += bfLo(v); x1 += bfHi(v);
    }
    atomicAdd(&out[(size_t)cur * HD + 2 * j], x0);
    atomicAdd(&out[(size_t)cur * HD + 2 * j + 1], x1);
}

extern "C" void kernel_launch(void* const* d_in, const int* in_sizes, int n_in,
                              void* d_out, int out_size, void* d_ws, size_t ws_size,
                              hipStream_t stream) {
    (void)n_in; (void)ws_size;
    const float* x   = (const float*)d_in[0];
    const float* Wfc = (const float*)d_in[1];
    const float* bfc = (const float*)d_in[2];
    const float* W1  = (const float*)d_in[3];
    const float* b1  = (const float*)d_in[4];
    const float* W2  = (const float*)d_in[5];
    const float* b2  = (const float*)d_in[6];
    const int* src   = (const int*)d_in[7];
    const int* dst   = (const int*)d_in[8];
    const int* gid   = (const int*)d_in[9];

    int N = in_sizes[0] / DIN;       // 100000
    int E = in_sizes[7];             // 1600000
    int nTiles = (N + 127) / 128;
    int B = (N + 255) >> 8;          // buckets of 256 nodes

    // workspace layout (~72 MB)
    u16* h = (u16*)d_ws;                          // N*128 bf16
    u16* z = h + (size_t)N * HD;                  // N*128 bf16
    int* off    = (int*)(z + (size_t)N * HD);     // N+1
    int* cursor = off + (N + 1);                  // N
    int* esrc   = cursor + N;                     // E
    int* bsums  = esrc + E;                       // 128
    int* bcnt   = bsums + 128;                    // 512
    int* boff   = bcnt + 512;                     // 513
    int* bcur   = boff + 513;                     // 512 (total ints even -> 8B aligned next)
    uint2* bpairs = (uint2*)(bcur + 512);         // E pairs

    int nScan = N + 1;
    int nb = (nScan + 1023) / 1024;

    // --- CSR build (bucketed) ---
    zero_i32_kernel<<<(nScan + 255) / 256, 256, 0, stream>>>(off, nScan);
    zero_i32_kernel<<<2, 256, 0, stream>>>(bcnt, 512);
    bhist_kernel<<<(E + 4095) / 4096, 256, 0, stream>>>(dst, bcnt, E);
    bscan_kernel<<<1, 512, 0, stream>>>(bcnt, boff, bcur, B);
    bfill_kernel<<<(E + 255) / 256, 256, 0, stream>>>(src, dst, bcur, bpairs, E);
    hist_kernel<<<(E + 255) / 256, 256, 0, stream>>>(dst, off, E);
    scan1_kernel<<<nb, 256, 0, stream>>>(off, bsums, nScan);
    scan2_kernel<<<1, 64, 0, stream>>>(bsums, nb);
    scan3_kernel<<<(nScan + 255) / 256, 256, 0, stream>>>(off, bsums, nScan);
    copy_i32_kernel<<<(N + 255) / 256, 256, 0, stream>>>(off, cursor, N);
    bscatter_kernel<<<B, 256, 0, stream>>>(bpairs, boff, cursor, esrc);

    // --- node projection (bf16 out) ---
    fc_kernel<<<512, 512, 0, stream>>>(x, Wfc, bfc, h, N, nTiles);

    // --- 3x GINConv ---
    for (int l = 0; l < 3; l++) {
        agg_kernel<<<(N + 3) / 4, 256, 0, stream>>>(h, off, esrc, z, N);
        mlp_mfma_kernel<<<512, 512, 0, stream>>>(z, W1 + (size_t)l * HD * HD,
                                                 b1 + (size_t)l * HD, z, N, nTiles, 1);
        mlp_mfma_kernel<<<512, 512, 0, stream>>>(z, W2 + (size_t)l * HD * HD,
                                                 b2 + (size_t)l * HD, h, N, nTiles, 0);
    }

    // --- per-graph sum pooling ---
    zero_f32_kernel<<<(out_size + 255) / 256, 256, 0, stream>>>((float*)d_out, out_size);
    pool_kernel<<<(N + 127) / 128, 64, 0, stream>>>(h, gid, (float*)d_out, N);
}

// Round 4
// 626.781 us; speedup vs baseline: 2.8609x; 1.8352x over previous
//
#include <hip/hip_runtime.h>

#define DIN 55
#define HD 128
#define EB 8192          // edges per partition block
#define NBKT 512         // radix buckets (dst >> 8)

typedef unsigned short u16;
typedef unsigned int u32;
typedef short short8 __attribute__((ext_vector_type(8)));
typedef float f32x4 __attribute__((ext_vector_type(4)));

// ---- bf16 helpers ----
__device__ __forceinline__ u16 f2bf(float f) {
    u32 u = __float_as_uint(f);
    u32 r = (u + 0x7FFFu + ((u >> 16) & 1u)) >> 16;
    return (u16)r;
}
__device__ __forceinline__ float bfLo(u32 u) { return __uint_as_float(u << 16); }
__device__ __forceinline__ float bfHi(u32 u) { return __uint_as_float(u & 0xFFFF0000u); }

// ---------------- utility kernels ----------------
__global__ void zero_i32_kernel(int* p, int n) {
    int i = blockIdx.x * blockDim.x + threadIdx.x;
    if (i < n) p[i] = 0;
}
__global__ void zero_f32_kernel(float* p, int n) {
    int i = blockIdx.x * blockDim.x + threadIdx.x;
    if (i < n) p[i] = 0.f;
}
__global__ void copy_i32_kernel(const int* a, int* b, int n) {
    int i = blockIdx.x * blockDim.x + threadIdx.x;
    if (i < n) b[i] = a[i];
}

// ---------------- generic hierarchical inclusive scan ----------------
__global__ __launch_bounds__(256) void scan1_kernel(int* data, int* bsums, int n) {
    __shared__ int sT[256];
    int t = threadIdx.x;
    int base = blockIdx.x * 1024 + t * 4;
    int v0 = (base + 0 < n) ? data[base + 0] : 0;
    int v1 = (base + 1 < n) ? data[base + 1] : 0;
    int v2 = (base + 2 < n) ? data[base + 2] : 0;
    int v3 = (base + 3 < n) ? data[base + 3] : 0;
    v1 += v0; v2 += v1; v3 += v2;
    sT[t] = v3;
    __syncthreads();
    for (int off = 1; off < 256; off <<= 1) {
        int x = (t >= off) ? sT[t - off] : 0;
        __syncthreads();
        sT[t] += x;
        __syncthreads();
    }
    int excl = (t == 0) ? 0 : sT[t - 1];
    if (base + 0 < n) data[base + 0] = v0 + excl;
    if (base + 1 < n) data[base + 1] = v1 + excl;
    if (base + 2 < n) data[base + 2] = v2 + excl;
    if (base + 3 < n) data[base + 3] = v3 + excl;
    if (t == 255) bsums[blockIdx.x] = sT[255];
}
__global__ void scan2_kernel(int* bsums, int nb) {
    if (threadIdx.x == 0 && blockIdx.x == 0) {
        int acc = 0;
        for (int i = 0; i < nb; i++) { int tv = bsums[i]; bsums[i] = acc; acc += tv; }
    }
}
__global__ void scan3_kernel(int* data, const int* __restrict__ bsums, int n) {
    int i = blockIdx.x * blockDim.x + threadIdx.x;
    if (i < n) data[i] += bsums[i >> 10];
}

// ---------------- radix partition of edges by dst>>8 (atomic-free positions) ----------------
// pass 1: per-block LDS histogram -> histT[bucket * nB + block]
__global__ __launch_bounds__(256) void rhist_kernel(const int* __restrict__ dst,
                                                    int* __restrict__ histT, int E, int nB) {
    __shared__ int hh[NBKT];
    int t = threadIdx.x;
    for (int i = t; i < NBKT; i += 256) hh[i] = 0;
    __syncthreads();
    int base = blockIdx.x * EB;
    int end = min(base + EB, E);
    for (int i = base + t; i < end; i += 256) atomicAdd(&hh[dst[i] >> 8], 1);
    __syncthreads();
    for (int b = t; b < NBKT; b += 256) histT[b * nB + blockIdx.x] = hh[b];
}

// extract per-bucket exclusive offsets from the scanned histT
__global__ void boff_kernel(const int* __restrict__ scanned, int* __restrict__ boff, int nB) {
    int b = blockIdx.x * blockDim.x + threadIdx.x;
    if (b == 0) boff[0] = 0;
    if (b < NBKT) boff[b + 1] = scanned[(b + 1) * nB - 1];
}

// pass 2: recompute LDS hist, derive exclusive bases, ticket with LDS atomics, write pairs
__global__ __launch_bounds__(256) void rpos_kernel(const int* __restrict__ src,
                                                   const int* __restrict__ dst,
                                                   const int* __restrict__ scanned,
                                                   uint2* __restrict__ bpairs, int E, int nB) {
    __shared__ int hh[NBKT];
    __shared__ int cur[NBKT];
    int t = threadIdx.x;
    for (int i = t; i < NBKT; i += 256) hh[i] = 0;
    __syncthreads();
    int base = blockIdx.x * EB;
    int end = min(base + EB, E);
    for (int i = base + t; i < end; i += 256) atomicAdd(&hh[dst[i] >> 8], 1);
    __syncthreads();
    for (int b = t; b < NBKT; b += 256)
        cur[b] = scanned[b * nB + blockIdx.x] - hh[b];   // exclusive global base
    __syncthreads();
    for (int i = base + t; i < end; i += 256) {
        int d = dst[i];
        int p = atomicAdd(&cur[d >> 8], 1);              // LDS ticket
        bpairs[p] = make_uint2((u32)src[i], (u32)d);
    }
}

// per-node histogram (counts at off[n+1])
__global__ void hist_kernel(const int* __restrict__ dst, int* __restrict__ cnt, int E) {
    int i = blockIdx.x * blockDim.x + threadIdx.x;
    if (i < E) atomicAdd(&cnt[dst[i] + 1], 1);
}

// per-bucket final scatter: target windows are L2-resident
__global__ __launch_bounds__(256) void bscatter_kernel(const uint2* __restrict__ bpairs,
                                                       const int* __restrict__ boff,
                                                       int* cursor, int* __restrict__ esrc) {
    int b = blockIdx.x;
    int lo = boff[b], hi = boff[b + 1];
    for (int i = lo + threadIdx.x; i < hi; i += 256) {
        uint2 u = bpairs[i];
        int p = atomicAdd(&cursor[u.y], 1);
        esrc[p] = (int)u.x;
    }
}

// ---------------- node projection: h = x @ W_fc + b_fc  (fp32 math, bf16 out) ----------------
__global__ __launch_bounds__(512, 2) void fc_kernel(const float* __restrict__ x,
                                                    const float* __restrict__ Wfc,
                                                    const float* __restrict__ bfc,
                                                    u16* __restrict__ h,
                                                    int N, int nTiles) {
    __shared__ float sW[DIN * HD];
    __shared__ float sX[128 * 56];
    for (int i = threadIdx.x; i < DIN * HD / 4; i += 512)
        ((float4*)sW)[i] = ((const float4*)Wfc)[i];
    const int c = threadIdx.x & 15;
    const int r = threadIdx.x >> 4;
    float4 bb0 = ((const float4*)bfc)[2 * c];
    float4 bb1 = ((const float4*)bfc)[2 * c + 1];

    for (int tile = blockIdx.x; tile < nTiles; tile += gridDim.x) {
        int base = tile * 128;
        int limit = min(128, N - base) * DIN;
        __syncthreads();
        for (int i = threadIdx.x; i < 128 * DIN; i += 512) {
            float v = (i < limit) ? x[(size_t)base * DIN + i] : 0.f;
            sX[(i / DIN) * 56 + (i % DIN)] = v;
        }
        __syncthreads();

        float acc[4][8];
#pragma unroll
        for (int ii = 0; ii < 4; ii++) {
            acc[ii][0] = bb0.x; acc[ii][1] = bb0.y; acc[ii][2] = bb0.z; acc[ii][3] = bb0.w;
            acc[ii][4] = bb1.x; acc[ii][5] = bb1.y; acc[ii][6] = bb1.z; acc[ii][7] = bb1.w;
        }
        const int n0 = r * 4;
#pragma unroll 5
        for (int k = 0; k < DIN; k++) {
            float4 w0 = *(const float4*)&sW[k * HD + c * 8];
            float4 w1 = *(const float4*)&sW[k * HD + c * 8 + 4];
            float av[4] = {sX[(n0 + 0) * 56 + k], sX[(n0 + 1) * 56 + k],
                           sX[(n0 + 2) * 56 + k], sX[(n0 + 3) * 56 + k]};
#pragma unroll
            for (int ii = 0; ii < 4; ii++) {
                acc[ii][0] += av[ii] * w0.x; acc[ii][1] += av[ii] * w0.y;
                acc[ii][2] += av[ii] * w0.z; acc[ii][3] += av[ii] * w0.w;
                acc[ii][4] += av[ii] * w1.x; acc[ii][5] += av[ii] * w1.y;
                acc[ii][6] += av[ii] * w1.z; acc[ii][7] += av[ii] * w1.w;
            }
        }
        int nvalid = N - base;
#pragma unroll
        for (int ii = 0; ii < 4; ii++) {
            if (n0 + ii < nvalid) {
                u32 p0 = (u32)f2bf(acc[ii][0]) | ((u32)f2bf(acc[ii][1]) << 16);
                u32 p1 = (u32)f2bf(acc[ii][2]) | ((u32)f2bf(acc[ii][3]) << 16);
                u32 p2 = (u32)f2bf(acc[ii][4]) | ((u32)f2bf(acc[ii][5]) << 16);
                u32 p3 = (u32)f2bf(acc[ii][6]) | ((u32)f2bf(acc[ii][7]) << 16);
                *(uint4*)&h[(size_t)(base + n0 + ii) * HD + c * 8] = make_uint4(p0, p1, p2, p3);
            }
        }
    }
}

// ---------------- edge aggregation: z[n] = h[n] + sum_{e} h[esrc[e]]  (bf16) ----------------
__global__ __launch_bounds__(256) void agg_kernel(const u16* __restrict__ h,
                                                  const int* __restrict__ off,
                                                  const int* __restrict__ esrc,
                                                  u16* __restrict__ z, int N) {
    int w = threadIdx.x >> 6, lane = threadIdx.x & 63;
    int n = blockIdx.x * 4 + w;
    if (n >= N) return;
    int s0 = off[n], s1 = off[n + 1];
    int epar = lane >> 5, q = lane & 31;
    float a0 = 0.f, a1 = 0.f, a2 = 0.f, a3 = 0.f;
    int t = s0;
    for (; t + 8 <= s1; t += 8) {
        int e0 = esrc[t + 0 + epar], e1 = esrc[t + 2 + epar];
        int e2 = esrc[t + 4 + epar], e3 = esrc[t + 6 + epar];
        uint2 v0 = *(const uint2*)&h[(size_t)e0 * HD + q * 4];
        uint2 v1 = *(const uint2*)&h[(size_t)e1 * HD + q * 4];
        uint2 v2 = *(const uint2*)&h[(size_t)e2 * HD + q * 4];
        uint2 v3 = *(const uint2*)&h[(size_t)e3 * HD + q * 4];
        a0 += bfLo(v0.x) + bfLo(v1.x) + bfLo(v2.x) + bfLo(v3.x);
        a1 += bfHi(v0.x) + bfHi(v1.x) + bfHi(v2.x) + bfHi(v3.x);
        a2 += bfLo(v0.y) + bfLo(v1.y) + bfLo(v2.y) + bfLo(v3.y);
        a3 += bfHi(v0.y) + bfHi(v1.y) + bfHi(v2.y) + bfHi(v3.y);
    }
    for (; t + 2 <= s1; t += 2) {
        int e0 = esrc[t + epar];
        uint2 v0 = *(const uint2*)&h[(size_t)e0 * HD + q * 4];
        a0 += bfLo(v0.x); a1 += bfHi(v0.x); a2 += bfLo(v0.y); a3 += bfHi(v0.y);
    }
    if (t < s1 && epar == 0) {
        int e0 = esrc[t];
        uint2 v0 = *(const uint2*)&h[(size_t)e0 * HD + q * 4];
        a0 += bfLo(v0.x); a1 += bfHi(v0.x); a2 += bfLo(v0.y); a3 += bfHi(v0.y);
    }
    a0 += __shfl_down(a0, 32);
    a1 += __shfl_down(a1, 32);
    a2 += __shfl_down(a2, 32);
    a3 += __shfl_down(a3, 32);
    if (epar == 0) {
        uint2 sv = *(const uint2*)&h[(size_t)n * HD + q * 4];
        a0 += bfLo(sv.x); a1 += bfHi(sv.x); a2 += bfLo(sv.y); a3 += bfHi(sv.y);
        u32 p0 = (u32)f2bf(a0) | ((u32)f2bf(a1) << 16);
        u32 p1 = (u32)f2bf(a2) | ((u32)f2bf(a3) << 16);
        *(uint2*)&z[(size_t)n * HD + q * 4] = make_uint2(p0, p1);
    }
}

// ---------------- MFMA MLP: out = act(in @ W + b), in/out bf16, W/b fp32 ----------------
__global__ __launch_bounds__(512, 4) void mlp_mfma_kernel(const u16* __restrict__ in,
                                                          const float* __restrict__ W,
                                                          const float* __restrict__ b,
                                                          u16* __restrict__ out,
                                                          int N, int nTiles, int relu) {
    __shared__ u16 sB[8 * 4 * 64 * 8];   // 32 KB: [ct][kc][slot][8]
    __shared__ u16 sA[16896];            // 33 KB: frags / W-row scratch 128x132

    const int t = threadIdx.x;
    for (int c = t; c < 128 * 32; c += 512) {
        int k = c >> 5, j4 = c & 31;
        float4 wv = ((const float4*)W)[c];
        u32 p0 = (u32)f2bf(wv.x) | ((u32)f2bf(wv.y) << 16);
        u32 p1 = (u32)f2bf(wv.z) | ((u32)f2bf(wv.w) << 16);
        *(uint2*)&sA[k * 132 + j4 * 4] = make_uint2(p0, p1);
    }
    __syncthreads();
    for (int e = t; e < 2048; e += 512) {
        int L = e & 63, g = e >> 6;
        int ct = g >> 2, kc = g & 3;
        int j = ct * 16 + (L & 15);
        int k0 = kc * 32 + ((L >> 4) << 3);
        short8 sv;
#pragma unroll
        for (int i = 0; i < 8; i++) sv[i] = (short)sA[(k0 + i) * 132 + j];
        int slot = L ^ (kc << 1);
        *(short8*)&sB[(((ct << 2) + kc) << 6 | slot) * 8] = sv;
    }

    const int w = t >> 6, lane = t & 63;
    const int rbase = (w & 3) << 5;
    const int cbase = (w >> 2) << 6;
    float bias[4];
#pragma unroll
    for (int ct = 0; ct < 4; ct++) bias[ct] = b[cbase + ct * 16 + (lane & 15)];

    for (int tile = blockIdx.x; tile < nTiles; tile += gridDim.x) {
        int base = tile * 128;
        int nvalid = N - base;
        __syncthreads();
        int limit = min(128, nvalid) * 16;
        for (int c = t; c < 2048; c += 512) {
            int n = c >> 4, k8 = c & 15;
            uint4 raw = make_uint4(0, 0, 0, 0);
            if (c < limit)
                raw = *(const uint4*)&in[((size_t)(base + n)) * HD + k8 * 8];
            int rt = n >> 4, kc = k8 >> 2;
            int L = ((k8 & 3) << 4) | (n & 15);
            int slot = L ^ (kc << 1);
            *(uint4*)&sA[(((rt << 2) + kc) << 6 | slot) * 8] = raw;
        }
        __syncthreads();

        short8 af[2][4];
#pragma unroll
        for (int rt = 0; rt < 2; rt++) {
            int rtg = (rbase >> 4) + rt;
#pragma unroll
            for (int kc = 0; kc < 4; kc++)
                af[rt][kc] = *(const short8*)&sA[(((rtg << 2) + kc) << 6 | (lane ^ (kc << 1))) * 8];
        }
        f32x4 acc[2][4];
#pragma unroll
        for (int rt = 0; rt < 2; rt++)
#pragma unroll
            for (int ct = 0; ct < 4; ct++) {
                acc[rt][ct][0] = bias[ct]; acc[rt][ct][1] = bias[ct];
                acc[rt][ct][2] = bias[ct]; acc[rt][ct][3] = bias[ct];
            }
#pragma unroll
        for (int ct = 0; ct < 4; ct++) {
            int ctg = (cbase >> 4) + ct;
#pragma unroll
            for (int kc = 0; kc < 4; kc++) {
                short8 bf = *(const short8*)&sB[(((ctg << 2) + kc) << 6 | (lane ^ (kc << 1))) * 8];
                acc[0][ct] = __builtin_amdgcn_mfma_f32_16x16x32_bf16(af[0][kc], bf, acc[0][ct], 0, 0, 0);
                acc[1][ct] = __builtin_amdgcn_mfma_f32_16x16x32_bf16(af[1][kc], bf, acc[1][ct], 0, 0, 0);
            }
        }
#pragma unroll
        for (int rt = 0; rt < 2; rt++) {
            int rowb = rbase + rt * 16 + ((lane >> 4) << 2);
#pragma unroll
            for (int ct = 0; ct < 4; ct++) {
                int col = cbase + ct * 16 + (lane & 15);
#pragma unroll
                for (int reg = 0; reg < 4; reg++) {
                    int row = rowb + reg;
                    if (row < nvalid) {
                        float v = acc[rt][ct][reg];
                        if (relu) v = fmaxf(v, 0.f);
                        out[(size_t)(base + row) * HD + col] = f2bf(v);
                    }
                }
            }
        }
    }
}

// ---------------- per-graph sum pool (bf16 in, fp32 atomics out) ----------------
__global__ __launch_bounds__(64) void pool_kernel(const u16* __restrict__ h,
                                                  const int* __restrict__ gid,
                                                  float* __restrict__ out, int N) {
    int j = threadIdx.x;
    int start = blockIdx.x * 128;
    if (start >= N) return;
    int end = min(start + 128, N);
    int cur = gid[start];
    float x0 = 0.f, x1 = 0.f;
    for (int n = start; n < end; n++) {
        int g = gid[n];
        if (g != cur) {
            atomicAdd(&out[(size_t)cur * HD + 2 * j], x0);
            atomicAdd(&out[(size_t)cur * HD + 2 * j + 1], x1);
            cur = g; x0 = 0.f; x1 = 0.f;
        }
        u32 v = *(const u32*)&h[(size_t)n * HD + j * 2];
        x0 += bfLo(v); x1 += bfHi(v);
    }
    atomicAdd(&out[(size_t)cur * HD + 2 * j], x0);
    atomicAdd(&out[(size_t)cur * HD + 2 * j + 1], x1);
}

extern "C" void kernel_launch(void* const* d_in, const int* in_sizes, int n_in,
                              void* d_out, int out_size, void* d_ws, size_t ws_size,
                              hipStream_t stream) {
    (void)n_in; (void)ws_size;
    const float* x   = (const float*)d_in[0];
    const float* Wfc = (const float*)d_in[1];
    const float* bfc = (const float*)d_in[2];
    const float* W1  = (const float*)d_in[3];
    const float* b1  = (const float*)d_in[4];
    const float* W2  = (const float*)d_in[5];
    const float* b2  = (const float*)d_in[6];
    const int* src   = (const int*)d_in[7];
    const int* dst   = (const int*)d_in[8];
    const int* gid   = (const int*)d_in[9];

    int N = in_sizes[0] / DIN;       // 100000
    int E = in_sizes[7];             // 1600000
    int nTiles = (N + 127) / 128;
    int nB = (E + EB - 1) / EB;      // partition blocks (196)
    int nScan2 = NBKT * nB;          // histT length
    int nb2 = (nScan2 + 1023) / 1024;

    // workspace layout (~72 MB)
    u16* h = (u16*)d_ws;                          // N*128 bf16
    u16* z = h + (size_t)N * HD;                  // N*128 bf16
    int* off    = (int*)(z + (size_t)N * HD);     // N+1
    int* cursor = off + (N + 1);                  // N
    int* esrc   = cursor + N;                     // E
    int* bsums  = esrc + E;                       // 256
    int* bsums2 = bsums + 256;                    // 256
    int* boff   = bsums2 + 256;                   // NBKT+1 (+pad)
    int* histT  = boff + NBKT + 4;                // NBKT*nB
    uint2* bpairs = (uint2*)((((uintptr_t)(histT + nScan2)) + 15) & ~(uintptr_t)15);

    int nScan = N + 1;
    int nb = (nScan + 1023) / 1024;

    // --- radix partition of edges by dst>>8 (no global atomics) ---
    rhist_kernel<<<nB, 256, 0, stream>>>(dst, histT, E, nB);
    scan1_kernel<<<nb2, 256, 0, stream>>>(histT, bsums2, nScan2);
    scan2_kernel<<<1, 64, 0, stream>>>(bsums2, nb2);
    scan3_kernel<<<(nScan2 + 255) / 256, 256, 0, stream>>>(histT, bsums2, nScan2);
    boff_kernel<<<2, 256, 0, stream>>>(histT, boff, nB);
    rpos_kernel<<<nB, 256, 0, stream>>>(src, dst, histT, bpairs, E, nB);

    // --- per-node CSR offsets ---
    zero_i32_kernel<<<(nScan + 255) / 256, 256, 0, stream>>>(off, nScan);
    hist_kernel<<<(E + 255) / 256, 256, 0, stream>>>(dst, off, E);
    scan1_kernel<<<nb, 256, 0, stream>>>(off, bsums, nScan);
    scan2_kernel<<<1, 64, 0, stream>>>(bsums, nb);
    scan3_kernel<<<(nScan + 255) / 256, 256, 0, stream>>>(off, bsums, nScan);
    copy_i32_kernel<<<(N + 255) / 256, 256, 0, stream>>>(off, cursor, N);
    bscatter_kernel<<<NBKT, 256, 0, stream>>>(bpairs, boff, cursor, esrc);

    // --- node projection (bf16 out) ---
    fc_kernel<<<512, 512, 0, stream>>>(x, Wfc, bfc, h, N, nTiles);

    // --- 3x GINConv ---
    for (int l = 0; l < 3; l++) {
        agg_kernel<<<(N + 3) / 4, 256, 0, stream>>>(h, off, esrc, z, N);
        mlp_mfma_kernel<<<512, 512, 0, stream>>>(z, W1 + (size_t)l * HD * HD,
                                                 b1 + (size_t)l * HD, z, N, nTiles, 1);
        mlp_mfma_kernel<<<512, 512, 0, stream>>>(z, W2 + (size_t)l * HD * HD,
                                                 b2 + (size_t)l * HD, h, N, nTiles, 0);
    }

    // --- per-graph sum pooling ---
    zero_f32_kernel<<<(out_size + 255) / 256, 256, 0, stream>>>((float*)d_out, out_size);
    pool_kernel<<<(N + 127) / 128, 64, 0, stream>>>(h, gid, (float*)d_out, N);
}

// Round 5
// 585.268 us; speedup vs baseline: 3.0639x; 1.0709x over previous
//
#include <hip/hip_runtime.h>

#define DIN 55
#define HD 128
#define EB 8192          // edges per partition block
#define NBKT 512         // radix buckets (dst >> 8)

typedef unsigned short u16;
typedef unsigned int u32;
typedef short short8 __attribute__((ext_vector_type(8)));
typedef float f32x4 __attribute__((ext_vector_type(4)));

// ---- bf16 helpers ----
__device__ __forceinline__ u16 f2bf(float f) {
    u32 u = __float_as_uint(f);
    u32 r = (u + 0x7FFFu + ((u >> 16) & 1u)) >> 16;
    return (u16)r;
}
__device__ __forceinline__ float bfLo(u32 u) { return __uint_as_float(u << 16); }
__device__ __forceinline__ float bfHi(u32 u) { return __uint_as_float(u & 0xFFFF0000u); }

// ---------------- utility kernels ----------------
__global__ void zero_i32_kernel(int* p, int n) {
    int i = blockIdx.x * blockDim.x + threadIdx.x;
    if (i < n) p[i] = 0;
}
__global__ void zero_f32_kernel(float* p, int n) {
    int i = blockIdx.x * blockDim.x + threadIdx.x;
    if (i < n) p[i] = 0.f;
}
__global__ void copy_i32_kernel(const int* a, int* b, int n) {
    int i = blockIdx.x * blockDim.x + threadIdx.x;
    if (i < n) b[i] = a[i];
}

// ---------------- generic hierarchical inclusive scan ----------------
__global__ __launch_bounds__(256) void scan1_kernel(int* data, int* bsums, int n) {
    __shared__ int sT[256];
    int t = threadIdx.x;
    int base = blockIdx.x * 1024 + t * 4;
    int v0 = (base + 0 < n) ? data[base + 0] : 0;
    int v1 = (base + 1 < n) ? data[base + 1] : 0;
    int v2 = (base + 2 < n) ? data[base + 2] : 0;
    int v3 = (base + 3 < n) ? data[base + 3] : 0;
    v1 += v0; v2 += v1; v3 += v2;
    sT[t] = v3;
    __syncthreads();
    for (int off = 1; off < 256; off <<= 1) {
        int x = (t >= off) ? sT[t - off] : 0;
        __syncthreads();
        sT[t] += x;
        __syncthreads();
    }
    int excl = (t == 0) ? 0 : sT[t - 1];
    if (base + 0 < n) data[base + 0] = v0 + excl;
    if (base + 1 < n) data[base + 1] = v1 + excl;
    if (base + 2 < n) data[base + 2] = v2 + excl;
    if (base + 3 < n) data[base + 3] = v3 + excl;
    if (t == 255) bsums[blockIdx.x] = sT[255];
}
// parallel exclusive scan of block sums (nb <= 1024) — replaces serial 1-thread walk
__global__ __launch_bounds__(1024) void scan2_kernel(int* bsums, int nb) {
    __shared__ int s[1024];
    int t = threadIdx.x;
    int v = (t < nb) ? bsums[t] : 0;
    s[t] = v;
    __syncthreads();
    for (int o = 1; o < 1024; o <<= 1) {
        int x = (t >= o) ? s[t - o] : 0;
        __syncthreads();
        s[t] += x;
        __syncthreads();
    }
    if (t < nb) bsums[t] = s[t] - v;   // exclusive
}
__global__ void scan3_kernel(int* data, const int* __restrict__ bsums, int n) {
    int i = blockIdx.x * blockDim.x + threadIdx.x;
    if (i < n) data[i] += bsums[i >> 10];
}

// ---------------- radix partition of edges by dst>>8 (atomic-free positions) ----------------
__global__ __launch_bounds__(256) void rhist_kernel(const int* __restrict__ dst,
                                                    int* __restrict__ histT, int E, int nB) {
    __shared__ int hh[NBKT];
    int t = threadIdx.x;
    for (int i = t; i < NBKT; i += 256) hh[i] = 0;
    __syncthreads();
    int base = blockIdx.x * EB;
    int end = min(base + EB, E);
    for (int i = base + t; i < end; i += 256) atomicAdd(&hh[dst[i] >> 8], 1);
    __syncthreads();
    for (int b = t; b < NBKT; b += 256) histT[b * nB + blockIdx.x] = hh[b];
}

__global__ void boff_kernel(const int* __restrict__ scanned, int* __restrict__ boff, int nB) {
    int b = blockIdx.x * blockDim.x + threadIdx.x;
    if (b == 0) boff[0] = 0;
    if (b < NBKT) boff[b + 1] = scanned[(b + 1) * nB - 1];
}

__global__ __launch_bounds__(256) void rpos_kernel(const int* __restrict__ src,
                                                   const int* __restrict__ dst,
                                                   const int* __restrict__ scanned,
                                                   uint2* __restrict__ bpairs, int E, int nB) {
    __shared__ int hh[NBKT];
    __shared__ int cur[NBKT];
    int t = threadIdx.x;
    for (int i = t; i < NBKT; i += 256) hh[i] = 0;
    __syncthreads();
    int base = blockIdx.x * EB;
    int end = min(base + EB, E);
    for (int i = base + t; i < end; i += 256) atomicAdd(&hh[dst[i] >> 8], 1);
    __syncthreads();
    for (int b = t; b < NBKT; b += 256)
        cur[b] = scanned[b * nB + blockIdx.x] - hh[b];
    __syncthreads();
    for (int i = base + t; i < end; i += 256) {
        int d = dst[i];
        int p = atomicAdd(&cur[d >> 8], 1);
        bpairs[p] = make_uint2((u32)src[i], (u32)d);
    }
}

__global__ void hist_kernel(const int* __restrict__ dst, int* __restrict__ cnt, int E) {
    int i = blockIdx.x * blockDim.x + threadIdx.x;
    if (i < E) atomicAdd(&cnt[dst[i] + 1], 1);
}

__global__ __launch_bounds__(256) void bscatter_kernel(const uint2* __restrict__ bpairs,
                                                       const int* __restrict__ boff,
                                                       int* cursor, int* __restrict__ esrc) {
    int b = blockIdx.x;
    int lo = boff[b], hi = boff[b + 1];
    for (int i = lo + threadIdx.x; i < hi; i += 256) {
        uint2 u = bpairs[i];
        int p = atomicAdd(&cursor[u.y], 1);
        esrc[p] = (int)u.x;
    }
}

// ---------------- node projection: h = x @ W_fc + b_fc  (fp32 math, bf16 out) ----------------
__global__ __launch_bounds__(512, 2) void fc_kernel(const float* __restrict__ x,
                                                    const float* __restrict__ Wfc,
                                                    const float* __restrict__ bfc,
                                                    u16* __restrict__ h,
                                                    int N, int nTiles) {
    __shared__ float sW[DIN * HD];
    __shared__ float sX[128 * 56];
    for (int i = threadIdx.x; i < DIN * HD / 4; i += 512)
        ((float4*)sW)[i] = ((const float4*)Wfc)[i];
    const int c = threadIdx.x & 15;
    const int r = threadIdx.x >> 4;
    float4 bb0 = ((const float4*)bfc)[2 * c];
    float4 bb1 = ((const float4*)bfc)[2 * c + 1];

    for (int tile = blockIdx.x; tile < nTiles; tile += gridDim.x) {
        int base = tile * 128;
        int limit = min(128, N - base) * DIN;
        __syncthreads();
        for (int i = threadIdx.x; i < 128 * DIN; i += 512) {
            float v = (i < limit) ? x[(size_t)base * DIN + i] : 0.f;
            sX[(i / DIN) * 56 + (i % DIN)] = v;
        }
        __syncthreads();

        float acc[4][8];
#pragma unroll
        for (int ii = 0; ii < 4; ii++) {
            acc[ii][0] = bb0.x; acc[ii][1] = bb0.y; acc[ii][2] = bb0.z; acc[ii][3] = bb0.w;
            acc[ii][4] = bb1.x; acc[ii][5] = bb1.y; acc[ii][6] = bb1.z; acc[ii][7] = bb1.w;
        }
        const int n0 = r * 4;
#pragma unroll 5
        for (int k = 0; k < DIN; k++) {
            float4 w0 = *(const float4*)&sW[k * HD + c * 8];
            float4 w1 = *(const float4*)&sW[k * HD + c * 8 + 4];
            float av[4] = {sX[(n0 + 0) * 56 + k], sX[(n0 + 1) * 56 + k],
                           sX[(n0 + 2) * 56 + k], sX[(n0 + 3) * 56 + k]};
#pragma unroll
            for (int ii = 0; ii < 4; ii++) {
                acc[ii][0] += av[ii] * w0.x; acc[ii][1] += av[ii] * w0.y;
                acc[ii][2] += av[ii] * w0.z; acc[ii][3] += av[ii] * w0.w;
                acc[ii][4] += av[ii] * w1.x; acc[ii][5] += av[ii] * w1.y;
                acc[ii][6] += av[ii] * w1.z; acc[ii][7] += av[ii] * w1.w;
            }
        }
        int nvalid = N - base;
#pragma unroll
        for (int ii = 0; ii < 4; ii++) {
            if (n0 + ii < nvalid) {
                u32 p0 = (u32)f2bf(acc[ii][0]) | ((u32)f2bf(acc[ii][1]) << 16);
                u32 p1 = (u32)f2bf(acc[ii][2]) | ((u32)f2bf(acc[ii][3]) << 16);
                u32 p2 = (u32)f2bf(acc[ii][4]) | ((u32)f2bf(acc[ii][5]) << 16);
                u32 p3 = (u32)f2bf(acc[ii][6]) | ((u32)f2bf(acc[ii][7]) << 16);
                *(uint4*)&h[(size_t)(base + n0 + ii) * HD + c * 8] = make_uint4(p0, p1, p2, p3);
            }
        }
    }
}

// ---------------- edge aggregation: z[n] = h[n] + sum_{e} h[esrc[e]]  (bf16) ----------------
// one wave per node; 16 lanes x 16B per edge row, 4 edge rows per instruction group
__global__ __launch_bounds__(256) void agg_kernel(const u16* __restrict__ h,
                                                  const int* __restrict__ off,
                                                  const int* __restrict__ esrc,
                                                  u16* __restrict__ z, int N) {
    int w = threadIdx.x >> 6, lane = threadIdx.x & 63;
    int n = blockIdx.x * 4 + w;
    if (n >= N) return;
    int s0 = off[n], s1 = off[n + 1];
    int g = lane >> 4, q = lane & 15;     // edge-slot g, feature-oct q (8 bf16 = 16 B)
    float a0 = 0.f, a1 = 0.f, a2 = 0.f, a3 = 0.f, a4 = 0.f, a5 = 0.f, a6 = 0.f, a7 = 0.f;
    int t = s0;
#define ACC8(V) { a0 += bfLo(V.x); a1 += bfHi(V.x); a2 += bfLo(V.y); a3 += bfHi(V.y); \
                  a4 += bfLo(V.z); a5 += bfHi(V.z); a6 += bfLo(V.w); a7 += bfHi(V.w); }
    for (; t + 16 <= s1; t += 16) {       // 4 x uint4 in flight
        int e0 = esrc[t + g], e1 = esrc[t + 4 + g];
        int e2 = esrc[t + 8 + g], e3 = esrc[t + 12 + g];
        uint4 v0 = *(const uint4*)&h[(size_t)e0 * HD + q * 8];
        uint4 v1 = *(const uint4*)&h[(size_t)e1 * HD + q * 8];
        uint4 v2 = *(const uint4*)&h[(size_t)e2 * HD + q * 8];
        uint4 v3 = *(const uint4*)&h[(size_t)e3 * HD + q * 8];
        ACC8(v0); ACC8(v1); ACC8(v2); ACC8(v3);
    }
    for (; t + 4 <= s1; t += 4) {
        int e0 = esrc[t + g];
        uint4 v0 = *(const uint4*)&h[(size_t)e0 * HD + q * 8];
        ACC8(v0);
    }
    if (t + g < s1) {
        int e0 = esrc[t + g];
        uint4 v0 = *(const uint4*)&h[(size_t)e0 * HD + q * 8];
        ACC8(v0);
    }
    if (g == 0) {                          // self term
        uint4 sv = *(const uint4*)&h[(size_t)n * HD + q * 8];
        ACC8(sv);
    }
#undef ACC8
    a0 += __shfl_down(a0, 32); a1 += __shfl_down(a1, 32);
    a2 += __shfl_down(a2, 32); a3 += __shfl_down(a3, 32);
    a4 += __shfl_down(a4, 32); a5 += __shfl_down(a5, 32);
    a6 += __shfl_down(a6, 32); a7 += __shfl_down(a7, 32);
    a0 += __shfl_down(a0, 16); a1 += __shfl_down(a1, 16);
    a2 += __shfl_down(a2, 16); a3 += __shfl_down(a3, 16);
    a4 += __shfl_down(a4, 16); a5 += __shfl_down(a5, 16);
    a6 += __shfl_down(a6, 16); a7 += __shfl_down(a7, 16);
    if (g == 0) {
        u32 p0 = (u32)f2bf(a0) | ((u32)f2bf(a1) << 16);
        u32 p1 = (u32)f2bf(a2) | ((u32)f2bf(a3) << 16);
        u32 p2 = (u32)f2bf(a4) | ((u32)f2bf(a5) << 16);
        u32 p3 = (u32)f2bf(a6) | ((u32)f2bf(a7) << 16);
        *(uint4*)&z[(size_t)n * HD + q * 8] = make_uint4(p0, p1, p2, p3);
    }
}

// ---------------- fused MLP pair: out = relu(in@W1+b1)@W2+b2, in/out bf16 ----------------
// 512 threads = 8 waves. Tile 128 nodes. GEMM1 -> LDS transpose (relu) -> GEMM2.
// LDS: sB1 32K + sB2 32K + sA 32K + sZ 34K = 130 KB -> 1 block/CU.
__global__ __launch_bounds__(512, 2) void mlp_pair_kernel(const u16* __restrict__ in,
                                                          const float* __restrict__ W1,
                                                          const float* __restrict__ b1,
                                                          const float* __restrict__ W2,
                                                          const float* __restrict__ b2,
                                                          u16* __restrict__ out,
                                                          int N, int nTiles) {
    __shared__ u16 sB1[16384];           // W1 frags [ct][kc][slot][8]
    __shared__ u16 sB2[16384];           // W2 frags
    __shared__ u16 sA[16384];            // input frags
    __shared__ u16 sZ[128 * 136];        // z1 row-major (pad 136) / W staging scratch

    const int t = threadIdx.x;
    // --- build W1 frags (stage fp32->bf16 rows into sZ scratch, then fragment) ---
    for (int wsel = 0; wsel < 2; wsel++) {
        const float* W = wsel ? W2 : W1;
        u16* sB = wsel ? sB2 : sB1;
        __syncthreads();
        for (int c = t; c < 128 * 32; c += 512) {
            int k = c >> 5, j4 = c & 31;
            float4 wv = ((const float4*)W)[c];
            u32 p0 = (u32)f2bf(wv.x) | ((u32)f2bf(wv.y) << 16);
            u32 p1 = (u32)f2bf(wv.z) | ((u32)f2bf(wv.w) << 16);
            *(uint2*)&sZ[k * 136 + j4 * 4] = make_uint2(p0, p1);
        }
        __syncthreads();
        for (int e = t; e < 2048; e += 512) {
            int L = e & 63, gq = e >> 6;
            int ct = gq >> 2, kc = gq & 3;
            int j = ct * 16 + (L & 15);
            int k0 = kc * 32 + ((L >> 4) << 3);
            short8 sv;
#pragma unroll
            for (int i = 0; i < 8; i++) sv[i] = (short)sZ[(k0 + i) * 136 + j];
            int slot = L ^ (kc << 1);
            *(short8*)&sB[(((ct << 2) + kc) << 6 | slot) * 8] = sv;
        }
    }

    const int w = t >> 6, lane = t & 63;
    const int rbase = (w & 3) << 5;      // 0,32,64,96
    const int cbase = (w >> 2) << 6;     // 0 or 64
    float bias1[4], bias2[4];
#pragma unroll
    for (int ct = 0; ct < 4; ct++) {
        bias1[ct] = b1[cbase + ct * 16 + (lane & 15)];
        bias2[ct] = b2[cbase + ct * 16 + (lane & 15)];
    }

    for (int tile = blockIdx.x; tile < nTiles; tile += gridDim.x) {
        int base = tile * 128;
        int nvalid = N - base;
        __syncthreads();   // previous tile fully done (also covers sB/sZ init on first iter)
        // --- stage input tile into A frags ---
        int limit = min(128, nvalid) * 16;
        for (int c = t; c < 2048; c += 512) {
            int n = c >> 4, k8 = c & 15;
            uint4 raw = make_uint4(0, 0, 0, 0);
            if (c < limit)
                raw = *(const uint4*)&in[((size_t)(base + n)) * HD + k8 * 8];
            int rt = n >> 4, kc = k8 >> 2;
            int L = ((k8 & 3) << 4) | (n & 15);
            int slot = L ^ (kc << 1);
            *(uint4*)&sA[(((rt << 2) + kc) << 6 | slot) * 8] = raw;
        }
        __syncthreads();

        // --- GEMM1 ---
        short8 af[2][4];
#pragma unroll
        for (int rt = 0; rt < 2; rt++) {
            int rtg = (rbase >> 4) + rt;
#pragma unroll
            for (int kc = 0; kc < 4; kc++)
                af[rt][kc] = *(const short8*)&sA[(((rtg << 2) + kc) << 6 | (lane ^ (kc << 1))) * 8];
        }
        f32x4 acc1[2][4];
#pragma unroll
        for (int rt = 0; rt < 2; rt++)
#pragma unroll
            for (int ct = 0; ct < 4; ct++) {
                acc1[rt][ct][0] = bias1[ct]; acc1[rt][ct][1] = bias1[ct];
                acc1[rt][ct][2] = bias1[ct]; acc1[rt][ct][3] = bias1[ct];
            }
#pragma unroll
        for (int ct = 0; ct < 4; ct++) {
            int ctg = (cbase >> 4) + ct;
#pragma unroll
            for (int kc = 0; kc < 4; kc++) {
                short8 bf = *(const short8*)&sB1[(((ctg << 2) + kc) << 6 | (lane ^ (kc << 1))) * 8];
                acc1[0][ct] = __builtin_amdgcn_mfma_f32_16x16x32_bf16(af[0][kc], bf, acc1[0][ct], 0, 0, 0);
                acc1[1][ct] = __builtin_amdgcn_mfma_f32_16x16x32_bf16(af[1][kc], bf, acc1[1][ct], 0, 0, 0);
            }
        }
        // --- transpose z1 = relu(acc1) into sZ (C-layout -> row-major) ---
#pragma unroll
        for (int rt = 0; rt < 2; rt++) {
            int rowb = rbase + rt * 16 + ((lane >> 4) << 2);
#pragma unroll
            for (int ct = 0; ct < 4; ct++) {
                int col = cbase + ct * 16 + (lane & 15);
#pragma unroll
                for (int reg = 0; reg < 4; reg++)
                    sZ[(rowb + reg) * 136 + col] = f2bf(fmaxf(acc1[rt][ct][reg], 0.f));
            }
        }
        __syncthreads();
        // --- GEMM2: A frags straight from row-major sZ ---
        short8 af2[2][4];
#pragma unroll
        for (int rt = 0; rt < 2; rt++) {
            int row = rbase + rt * 16 + (lane & 15);
#pragma unroll
            for (int kc = 0; kc < 4; kc++)
                af2[rt][kc] = *(const short8*)&sZ[row * 136 + kc * 32 + ((lane >> 4) << 3)];
        }
        f32x4 acc2[2][4];
#pragma unroll
        for (int rt = 0; rt < 2; rt++)
#pragma unroll
            for (int ct = 0; ct < 4; ct++) {
                acc2[rt][ct][0] = bias2[ct]; acc2[rt][ct][1] = bias2[ct];
                acc2[rt][ct][2] = bias2[ct]; acc2[rt][ct][3] = bias2[ct];
            }
#pragma unroll
        for (int ct = 0; ct < 4; ct++) {
            int ctg = (cbase >> 4) + ct;
#pragma unroll
            for (int kc = 0; kc < 4; kc++) {
                short8 bf = *(const short8*)&sB2[(((ctg << 2) + kc) << 6 | (lane ^ (kc << 1))) * 8];
                acc2[0][ct] = __builtin_amdgcn_mfma_f32_16x16x32_bf16(af2[0][kc], bf, acc2[0][ct], 0, 0, 0);
                acc2[1][ct] = __builtin_amdgcn_mfma_f32_16x16x32_bf16(af2[1][kc], bf, acc2[1][ct], 0, 0, 0);
            }
        }
        // --- epilogue ---
#pragma unroll
        for (int rt = 0; rt < 2; rt++) {
            int rowb = rbase + rt * 16 + ((lane >> 4) << 2);
#pragma unroll
            for (int ct = 0; ct < 4; ct++) {
                int col = cbase + ct * 16 + (lane & 15);
#pragma unroll
                for (int reg = 0; reg < 4; reg++) {
                    int row = rowb + reg;
                    if (row < nvalid)
                        out[(size_t)(base + row) * HD + col] = f2bf(acc2[rt][ct][reg]);
                }
            }
        }
    }
}

// ---------------- per-graph sum pool (bf16 in, fp32 atomics out) ----------------
__global__ __launch_bounds__(64) void pool_kernel(const u16* __restrict__ h,
                                                  const int* __restrict__ gid,
                                                  float* __restrict__ out, int N) {
    int j = threadIdx.x;
    int start = blockIdx.x * 128;
    if (start >= N) return;
    int end = min(start + 128, N);
    int cur = gid[start];
    float x0 = 0.f, x1 = 0.f;
    for (int n = start; n < end; n++) {
        int g = gid[n];
        if (g != cur) {
            atomicAdd(&out[(size_t)cur * HD + 2 * j], x0);
            atomicAdd(&out[(size_t)cur * HD + 2 * j + 1], x1);
            cur = g; x0 = 0.f; x1 = 0.f;
        }
        u32 v = *(const u32*)&h[(size_t)n * HD + j * 2];
        x0 += bfLo(v); x1 += bfHi(v);
    }
    atomicAdd(&out[(size_t)cur * HD + 2 * j], x0);
    atomicAdd(&out[(size_t)cur * HD + 2 * j + 1], x1);
}

extern "C" void kernel_launch(void* const* d_in, const int* in_sizes, int n_in,
                              void* d_out, int out_size, void* d_ws, size_t ws_size,
                              hipStream_t stream) {
    (void)n_in; (void)ws_size;
    const float* x   = (const float*)d_in[0];
    const float* Wfc = (const float*)d_in[1];
    const float* bfc = (const float*)d_in[2];
    const float* W1  = (const float*)d_in[3];
    const float* b1  = (const float*)d_in[4];
    const float* W2  = (const float*)d_in[5];
    const float* b2  = (const float*)d_in[6];
    const int* src   = (const int*)d_in[7];
    const int* dst   = (const int*)d_in[8];
    const int* gid   = (const int*)d_in[9];

    int N = in_sizes[0] / DIN;       // 100000
    int E = in_sizes[7];             // 1600000
    int nTiles = (N + 127) / 128;
    int nB = (E + EB - 1) / EB;      // partition blocks (196)
    int nScan2 = NBKT * nB;          // histT length
    int nb2 = (nScan2 + 1023) / 1024;

    // workspace layout (~72 MB)
    u16* h = (u16*)d_ws;                          // N*128 bf16
    u16* z = h + (size_t)N * HD;                  // N*128 bf16
    int* off    = (int*)(z + (size_t)N * HD);     // N+1
    int* cursor = off + (N + 1);                  // N
    int* esrc   = cursor + N;                     // E
    int* bsums  = esrc + E;                       // 256
    int* bsums2 = bsums + 256;                    // 256
    int* boff   = bsums2 + 256;                   // NBKT+1 (+pad)
    int* histT  = boff + NBKT + 4;                // NBKT*nB
    uint2* bpairs = (uint2*)((((uintptr_t)(histT + nScan2)) + 15) & ~(uintptr_t)15);

    int nScan = N + 1;
    int nb = (nScan + 1023) / 1024;

    // --- radix partition of edges by dst>>8 (no global atomics) ---
    rhist_kernel<<<nB, 256, 0, stream>>>(dst, histT, E, nB);
    scan1_kernel<<<nb2, 256, 0, stream>>>(histT, bsums2, nScan2);
    scan2_kernel<<<1, 1024, 0, stream>>>(bsums2, nb2);
    scan3_kernel<<<(nScan2 + 255) / 256, 256, 0, stream>>>(histT, bsums2, nScan2);
    boff_kernel<<<2, 256, 0, stream>>>(histT, boff, nB);
    rpos_kernel<<<nB, 256, 0, stream>>>(src, dst, histT, bpairs, E, nB);

    // --- per-node CSR offsets ---
    zero_i32_kernel<<<(nScan + 255) / 256, 256, 0, stream>>>(off, nScan);
    hist_kernel<<<(E + 255) / 256, 256, 0, stream>>>(dst, off, E);
    scan1_kernel<<<nb, 256, 0, stream>>>(off, bsums, nScan);
    scan2_kernel<<<1, 1024, 0, stream>>>(bsums, nb);
    scan3_kernel<<<(nScan + 255) / 256, 256, 0, stream>>>(off, bsums, nScan);
    copy_i32_kernel<<<(N + 255) / 256, 256, 0, stream>>>(off, cursor, N);
    bscatter_kernel<<<NBKT, 256, 0, stream>>>(bpairs, boff, cursor, esrc);

    // --- node projection (bf16 out) ---
    fc_kernel<<<512, 512, 0, stream>>>(x, Wfc, bfc, h, N, nTiles);

    // --- 3x GINConv (agg + fused MLP pair) ---
    for (int l = 0; l < 3; l++) {
        agg_kernel<<<(N + 3) / 4, 256, 0, stream>>>(h, off, esrc, z, N);
        mlp_pair_kernel<<<256, 512, 0, stream>>>(z, W1 + (size_t)l * HD * HD,
                                                 b1 + (size_t)l * HD,
                                                 W2 + (size_t)l * HD * HD,
                                                 b2 + (size_t)l * HD, h, N, nTiles);
    }

    // --- per-graph sum pooling ---
    zero_f32_kernel<<<(out_size + 255) / 256, 256, 0, stream>>>((float*)d_out, out_size);
    pool_kernel<<<(N + 127) / 128, 64, 0, stream>>>(h, gid, (float*)d_out, N);
}

// Round 6
// 503.722 us; speedup vs baseline: 3.5599x; 1.1619x over previous
//
#include <hip/hip_runtime.h>

#define DIN 55
#define HD 128
#define EB 8192          // edges per partition block
#define NBKT 512         // radix buckets (dst >> 8)

typedef unsigned short u16;
typedef unsigned int u32;
typedef short short8 __attribute__((ext_vector_type(8)));
typedef float f32x4 __attribute__((ext_vector_type(4)));

// ---- bf16 helpers ----
__device__ __forceinline__ u16 f2bf(float f) {
    u32 u = __float_as_uint(f);
    u32 r = (u + 0x7FFFu + ((u >> 16) & 1u)) >> 16;
    return (u16)r;
}
__device__ __forceinline__ float bfLo(u32 u) { return __uint_as_float(u << 16); }
__device__ __forceinline__ float bfHi(u32 u) { return __uint_as_float(u & 0xFFFF0000u); }

// ---------------- utility kernels ----------------
__global__ void zero_f32_kernel(float* p, int n) {
    int i = blockIdx.x * blockDim.x + threadIdx.x;
    if (i < n) p[i] = 0.f;
}

// ---------------- generic hierarchical inclusive scan ----------------
__global__ __launch_bounds__(256) void scan1_kernel(int* data, int* bsums, int n) {
    __shared__ int sT[256];
    int t = threadIdx.x;
    int base = blockIdx.x * 1024 + t * 4;
    int v0 = (base + 0 < n) ? data[base + 0] : 0;
    int v1 = (base + 1 < n) ? data[base + 1] : 0;
    int v2 = (base + 2 < n) ? data[base + 2] : 0;
    int v3 = (base + 3 < n) ? data[base + 3] : 0;
    v1 += v0; v2 += v1; v3 += v2;
    sT[t] = v3;
    __syncthreads();
    for (int off = 1; off < 256; off <<= 1) {
        int x = (t >= off) ? sT[t - off] : 0;
        __syncthreads();
        sT[t] += x;
        __syncthreads();
    }
    int excl = (t == 0) ? 0 : sT[t - 1];
    if (base + 0 < n) data[base + 0] = v0 + excl;
    if (base + 1 < n) data[base + 1] = v1 + excl;
    if (base + 2 < n) data[base + 2] = v2 + excl;
    if (base + 3 < n) data[base + 3] = v3 + excl;
    if (t == 255) bsums[blockIdx.x] = sT[255];
}
// parallel exclusive scan of block sums (nb <= 1024)
__global__ __launch_bounds__(1024) void scan2_kernel(int* bsums, int nb) {
    __shared__ int s[1024];
    int t = threadIdx.x;
    int v = (t < nb) ? bsums[t] : 0;
    s[t] = v;
    __syncthreads();
    for (int o = 1; o < 1024; o <<= 1) {
        int x = (t >= o) ? s[t - o] : 0;
        __syncthreads();
        s[t] += x;
        __syncthreads();
    }
    if (t < nb) bsums[t] = s[t] - v;   // exclusive
}
__global__ void scan3_kernel(int* data, const int* __restrict__ bsums, int n) {
    int i = blockIdx.x * blockDim.x + threadIdx.x;
    if (i < n) data[i] += bsums[i >> 10];
}

// ---------------- radix partition of edges by dst>>8 (atomic-free positions) ----------------
__global__ __launch_bounds__(256) void rhist_kernel(const int* __restrict__ dst,
                                                    int* __restrict__ histT, int E, int nB) {
    __shared__ int hh[NBKT];
    int t = threadIdx.x;
    for (int i = t; i < NBKT; i += 256) hh[i] = 0;
    __syncthreads();
    int base = blockIdx.x * EB;
    int end = min(base + EB, E);
    for (int i = base + t; i < end; i += 256) atomicAdd(&hh[dst[i] >> 8], 1);
    __syncthreads();
    for (int b = t; b < NBKT; b += 256) histT[b * nB + blockIdx.x] = hh[b];
}

__global__ void boff_kernel(const int* __restrict__ scanned, int* __restrict__ boff, int nB) {
    int b = blockIdx.x * blockDim.x + threadIdx.x;
    if (b == 0) boff[0] = 0;
    if (b < NBKT) boff[b + 1] = scanned[(b + 1) * nB - 1];
}

// pass 2: ticket with LDS atomics, write packed pairs (src<<8 | dst&255)
__global__ __launch_bounds__(256) void rpos_kernel(const int* __restrict__ src,
                                                   const int* __restrict__ dst,
                                                   const int* __restrict__ scanned,
                                                   u32* __restrict__ bpairs, int E, int nB) {
    __shared__ int hh[NBKT];
    __shared__ int cur[NBKT];
    int t = threadIdx.x;
    for (int i = t; i < NBKT; i += 256) hh[i] = 0;
    __syncthreads();
    int base = blockIdx.x * EB;
    int end = min(base + EB, E);
    for (int i = base + t; i < end; i += 256) atomicAdd(&hh[dst[i] >> 8], 1);
    __syncthreads();
    for (int b = t; b < NBKT; b += 256)
        cur[b] = scanned[b * nB + blockIdx.x] - hh[b];
    __syncthreads();
    for (int i = base + t; i < end; i += 256) {
        int d = dst[i];
        int p = atomicAdd(&cur[d >> 8], 1);
        bpairs[p] = ((u32)src[i] << 8) | (u32)(d & 255);
    }
}

// per-node counts from bucket-partitioned pairs (LDS atomics only) -> off[n+1]
__global__ __launch_bounds__(256) void bcount_kernel(const u32* __restrict__ bpairs,
                                                     const int* __restrict__ boff,
                                                     int* __restrict__ off, int N) {
    __shared__ int cnt[256];
    int b = blockIdx.x, t = threadIdx.x;
    cnt[t] = 0;
    __syncthreads();
    int lo = boff[b], hi = boff[b + 1];
    for (int i = lo + t; i < hi; i += 256) atomicAdd(&cnt[bpairs[i] & 255u], 1);
    __syncthreads();
    int n = b * 256 + t;
    if (n < N) off[n + 1] = cnt[t];
    if (b == 0 && t == 0) off[0] = 0;
}

// final scatter with LDS cursors (no global atomics)
__global__ __launch_bounds__(256) void bscatter_kernel(const u32* __restrict__ bpairs,
                                                       const int* __restrict__ boff,
                                                       const int* __restrict__ off,
                                                       int* __restrict__ esrc, int N) {
    __shared__ int cur[256];
    int b = blockIdx.x, t = threadIdx.x;
    int n = b * 256 + t;
    cur[t] = (n < N) ? off[n] : 0;
    __syncthreads();
    int lo = boff[b], hi = boff[b + 1];
    for (int i = lo + t; i < hi; i += 256) {
        u32 v = bpairs[i];
        int p = atomicAdd(&cur[v & 255u], 1);
        esrc[p] = (int)(v >> 8);
    }
}

// ---------------- node projection: h = x @ W_fc + b_fc  (fp32 math, bf16 out) ----------------
__global__ __launch_bounds__(512, 2) void fc_kernel(const float* __restrict__ x,
                                                    const float* __restrict__ Wfc,
                                                    const float* __restrict__ bfc,
                                                    u16* __restrict__ h,
                                                    int N, int nTiles) {
    __shared__ float sW[DIN * HD];
    __shared__ float sX[128 * 56];
    for (int i = threadIdx.x; i < DIN * HD / 4; i += 512)
        ((float4*)sW)[i] = ((const float4*)Wfc)[i];
    const int c = threadIdx.x & 15;
    const int r = threadIdx.x >> 4;
    float4 bb0 = ((const float4*)bfc)[2 * c];
    float4 bb1 = ((const float4*)bfc)[2 * c + 1];

    for (int tile = blockIdx.x; tile < nTiles; tile += gridDim.x) {
        int base = tile * 128;
        int limit = min(128, N - base) * DIN;
        __syncthreads();
        for (int i = threadIdx.x; i < 128 * DIN; i += 512) {
            float v = (i < limit) ? x[(size_t)base * DIN + i] : 0.f;
            sX[(i / DIN) * 56 + (i % DIN)] = v;
        }
        __syncthreads();

        float acc[4][8];
#pragma unroll
        for (int ii = 0; ii < 4; ii++) {
            acc[ii][0] = bb0.x; acc[ii][1] = bb0.y; acc[ii][2] = bb0.z; acc[ii][3] = bb0.w;
            acc[ii][4] = bb1.x; acc[ii][5] = bb1.y; acc[ii][6] = bb1.z; acc[ii][7] = bb1.w;
        }
        const int n0 = r * 4;
#pragma unroll 5
        for (int k = 0; k < DIN; k++) {
            float4 w0 = *(const float4*)&sW[k * HD + c * 8];
            float4 w1 = *(const float4*)&sW[k * HD + c * 8 + 4];
            float av[4] = {sX[(n0 + 0) * 56 + k], sX[(n0 + 1) * 56 + k],
                           sX[(n0 + 2) * 56 + k], sX[(n0 + 3) * 56 + k]};
#pragma unroll
            for (int ii = 0; ii < 4; ii++) {
                acc[ii][0] += av[ii] * w0.x; acc[ii][1] += av[ii] * w0.y;
                acc[ii][2] += av[ii] * w0.z; acc[ii][3] += av[ii] * w0.w;
                acc[ii][4] += av[ii] * w1.x; acc[ii][5] += av[ii] * w1.y;
                acc[ii][6] += av[ii] * w1.z; acc[ii][7] += av[ii] * w1.w;
            }
        }
        int nvalid = N - base;
#pragma unroll
        for (int ii = 0; ii < 4; ii++) {
            if (n0 + ii < nvalid) {
                u32 p0 = (u32)f2bf(acc[ii][0]) | ((u32)f2bf(acc[ii][1]) << 16);
                u32 p1 = (u32)f2bf(acc[ii][2]) | ((u32)f2bf(acc[ii][3]) << 16);
                u32 p2 = (u32)f2bf(acc[ii][4]) | ((u32)f2bf(acc[ii][5]) << 16);
                u32 p3 = (u32)f2bf(acc[ii][6]) | ((u32)f2bf(acc[ii][7]) << 16);
                *(uint4*)&h[(size_t)(base + n0 + ii) * HD + c * 8] = make_uint4(p0, p1, p2, p3);
            }
        }
    }
}

// ---------------- edge aggregation: z[n] = h[n] + sum_{e} h[esrc[e]]  (bf16) ----------------
__global__ __launch_bounds__(256) void agg_kernel(const u16* __restrict__ h,
                                                  const int* __restrict__ off,
                                                  const int* __restrict__ esrc,
                                                  u16* __restrict__ z, int N) {
    int w = threadIdx.x >> 6, lane = threadIdx.x & 63;
    int n = blockIdx.x * 4 + w;
    if (n >= N) return;
    int s0 = off[n], s1 = off[n + 1];
    int g = lane >> 4, q = lane & 15;
    float a0 = 0.f, a1 = 0.f, a2 = 0.f, a3 = 0.f, a4 = 0.f, a5 = 0.f, a6 = 0.f, a7 = 0.f;
    int t = s0;
#define ACC8(V) { a0 += bfLo(V.x); a1 += bfHi(V.x); a2 += bfLo(V.y); a3 += bfHi(V.y); \
                  a4 += bfLo(V.z); a5 += bfHi(V.z); a6 += bfLo(V.w); a7 += bfHi(V.w); }
    for (; t + 16 <= s1; t += 16) {
        int e0 = esrc[t + g], e1 = esrc[t + 4 + g];
        int e2 = esrc[t + 8 + g], e3 = esrc[t + 12 + g];
        uint4 v0 = *(const uint4*)&h[(size_t)e0 * HD + q * 8];
        uint4 v1 = *(const uint4*)&h[(size_t)e1 * HD + q * 8];
        uint4 v2 = *(const uint4*)&h[(size_t)e2 * HD + q * 8];
        uint4 v3 = *(const uint4*)&h[(size_t)e3 * HD + q * 8];
        ACC8(v0); ACC8(v1); ACC8(v2); ACC8(v3);
    }
    for (; t + 4 <= s1; t += 4) {
        int e0 = esrc[t + g];
        uint4 v0 = *(const uint4*)&h[(size_t)e0 * HD + q * 8];
        ACC8(v0);
    }
    if (t + g < s1) {
        int e0 = esrc[t + g];
        uint4 v0 = *(const uint4*)&h[(size_t)e0 * HD + q * 8];
        ACC8(v0);
    }
    if (g == 0) {
        uint4 sv = *(const uint4*)&h[(size_t)n * HD + q * 8];
        ACC8(sv);
    }
#undef ACC8
    a0 += __shfl_down(a0, 32); a1 += __shfl_down(a1, 32);
    a2 += __shfl_down(a2, 32); a3 += __shfl_down(a3, 32);
    a4 += __shfl_down(a4, 32); a5 += __shfl_down(a5, 32);
    a6 += __shfl_down(a6, 32); a7 += __shfl_down(a7, 32);
    a0 += __shfl_down(a0, 16); a1 += __shfl_down(a1, 16);
    a2 += __shfl_down(a2, 16); a3 += __shfl_down(a3, 16);
    a4 += __shfl_down(a4, 16); a5 += __shfl_down(a5, 16);
    a6 += __shfl_down(a6, 16); a7 += __shfl_down(a7, 16);
    if (g == 0) {
        u32 p0 = (u32)f2bf(a0) | ((u32)f2bf(a1) << 16);
        u32 p1 = (u32)f2bf(a2) | ((u32)f2bf(a3) << 16);
        u32 p2 = (u32)f2bf(a4) | ((u32)f2bf(a5) << 16);
        u32 p3 = (u32)f2bf(a6) | ((u32)f2bf(a7) << 16);
        *(uint4*)&z[(size_t)n * HD + q * 8] = make_uint4(p0, p1, p2, p3);
    }
}

// ---------------- fused MLP pair: out = relu(in@W1+b1)@W2+b2, in/out bf16 ----------------
__global__ __launch_bounds__(512, 2) void mlp_pair_kernel(const u16* __restrict__ in,
                                                          const float* __restrict__ W1,
                                                          const float* __restrict__ b1,
                                                          const float* __restrict__ W2,
                                                          const float* __restrict__ b2,
                                                          u16* __restrict__ out,
                                                          int N, int nTiles) {
    __shared__ u16 sB1[16384];
    __shared__ u16 sB2[16384];
    __shared__ u16 sA[16384];
    __shared__ u16 sZ[128 * 136];

    const int t = threadIdx.x;
    for (int wsel = 0; wsel < 2; wsel++) {
        const float* W = wsel ? W2 : W1;
        u16* sB = wsel ? sB2 : sB1;
        __syncthreads();
        for (int c = t; c < 128 * 32; c += 512) {
            int k = c >> 5, j4 = c & 31;
            float4 wv = ((const float4*)W)[c];
            u32 p0 = (u32)f2bf(wv.x) | ((u32)f2bf(wv.y) << 16);
            u32 p1 = (u32)f2bf(wv.z) | ((u32)f2bf(wv.w) << 16);
            *(uint2*)&sZ[k * 136 + j4 * 4] = make_uint2(p0, p1);
        }
        __syncthreads();
        for (int e = t; e < 2048; e += 512) {
            int L = e & 63, gq = e >> 6;
            int ct = gq >> 2, kc = gq & 3;
            int j = ct * 16 + (L & 15);
            int k0 = kc * 32 + ((L >> 4) << 3);
            short8 sv;
#pragma unroll
            for (int i = 0; i < 8; i++) sv[i] = (short)sZ[(k0 + i) * 136 + j];
            int slot = L ^ (kc << 1);
            *(short8*)&sB[(((ct << 2) + kc) << 6 | slot) * 8] = sv;
        }
    }

    const int w = t >> 6, lane = t & 63;
    const int rbase = (w & 3) << 5;
    const int cbase = (w >> 2) << 6;
    float bias1[4], bias2[4];
#pragma unroll
    for (int ct = 0; ct < 4; ct++) {
        bias1[ct] = b1[cbase + ct * 16 + (lane & 15)];
        bias2[ct] = b2[cbase + ct * 16 + (lane & 15)];
    }

    for (int tile = blockIdx.x; tile < nTiles; tile += gridDim.x) {
        int base = tile * 128;
        int nvalid = N - base;
        __syncthreads();
        int limit = min(128, nvalid) * 16;
        for (int c = t; c < 2048; c += 512) {
            int n = c >> 4, k8 = c & 15;
            uint4 raw = make_uint4(0, 0, 0, 0);
            if (c < limit)
                raw = *(const uint4*)&in[((size_t)(base + n)) * HD + k8 * 8];
            int rt = n >> 4, kc = k8 >> 2;
            int L = ((k8 & 3) << 4) | (n & 15);
            int slot = L ^ (kc << 1);
            *(uint4*)&sA[(((rt << 2) + kc) << 6 | slot) * 8] = raw;
        }
        __syncthreads();

        short8 af[2][4];
#pragma unroll
        for (int rt = 0; rt < 2; rt++) {
            int rtg = (rbase >> 4) + rt;
#pragma unroll
            for (int kc = 0; kc < 4; kc++)
                af[rt][kc] = *(const short8*)&sA[(((rtg << 2) + kc) << 6 | (lane ^ (kc << 1))) * 8];
        }
        f32x4 acc1[2][4];
#pragma unroll
        for (int rt = 0; rt < 2; rt++)
#pragma unroll
            for (int ct = 0; ct < 4; ct++) {
                acc1[rt][ct][0] = bias1[ct]; acc1[rt][ct][1] = bias1[ct];
                acc1[rt][ct][2] = bias1[ct]; acc1[rt][ct][3] = bias1[ct];
            }
#pragma unroll
        for (int ct = 0; ct < 4; ct++) {
            int ctg = (cbase >> 4) + ct;
#pragma unroll
            for (int kc = 0; kc < 4; kc++) {
                short8 bf = *(const short8*)&sB1[(((ctg << 2) + kc) << 6 | (lane ^ (kc << 1))) * 8];
                acc1[0][ct] = __builtin_amdgcn_mfma_f32_16x16x32_bf16(af[0][kc], bf, acc1[0][ct], 0, 0, 0);
                acc1[1][ct] = __builtin_amdgcn_mfma_f32_16x16x32_bf16(af[1][kc], bf, acc1[1][ct], 0, 0, 0);
            }
        }
#pragma unroll
        for (int rt = 0; rt < 2; rt++) {
            int rowb = rbase + rt * 16 + ((lane >> 4) << 2);
#pragma unroll
            for (int ct = 0; ct < 4; ct++) {
                int col = cbase + ct * 16 + (lane & 15);
#pragma unroll
                for (int reg = 0; reg < 4; reg++)
                    sZ[(rowb + reg) * 136 + col] = f2bf(fmaxf(acc1[rt][ct][reg], 0.f));
            }
        }
        __syncthreads();
        short8 af2[2][4];
#pragma unroll
        for (int rt = 0; rt < 2; rt++) {
            int row = rbase + rt * 16 + (lane & 15);
#pragma unroll
            for (int kc = 0; kc < 4; kc++)
                af2[rt][kc] = *(const short8*)&sZ[row * 136 + kc * 32 + ((lane >> 4) << 3)];
        }
        f32x4 acc2[2][4];
#pragma unroll
        for (int rt = 0; rt < 2; rt++)
#pragma unroll
            for (int ct = 0; ct < 4; ct++) {
                acc2[rt][ct][0] = bias2[ct]; acc2[rt][ct][1] = bias2[ct];
                acc2[rt][ct][2] = bias2[ct]; acc2[rt][ct][3] = bias2[ct];
            }
#pragma unroll
        for (int ct = 0; ct < 4; ct++) {
            int ctg = (cbase >> 4) + ct;
#pragma unroll
            for (int kc = 0; kc < 4; kc++) {
                short8 bf = *(const short8*)&sB2[(((ctg << 2) + kc) << 6 | (lane ^ (kc << 1))) * 8];
                acc2[0][ct] = __builtin_amdgcn_mfma_f32_16x16x32_bf16(af2[0][kc], bf, acc2[0][ct], 0, 0, 0);
                acc2[1][ct] = __builtin_amdgcn_mfma_f32_16x16x32_bf16(af2[1][kc], bf, acc2[1][ct], 0, 0, 0);
            }
        }
#pragma unroll
        for (int rt = 0; rt < 2; rt++) {
            int rowb = rbase + rt * 16 + ((lane >> 4) << 2);
#pragma unroll
            for (int ct = 0; ct < 4; ct++) {
                int col = cbase + ct * 16 + (lane & 15);
#pragma unroll
                for (int reg = 0; reg < 4; reg++) {
                    int row = rowb + reg;
                    if (row < nvalid)
                        out[(size_t)(base + row) * HD + col] = f2bf(acc2[rt][ct][reg]);
                }
            }
        }
    }
}

// ---------------- per-graph sum pool (bf16 in, fp32 atomics out) ----------------
__global__ __launch_bounds__(64) void pool_kernel(const u16* __restrict__ h,
                                                  const int* __restrict__ gid,
                                                  float* __restrict__ out, int N) {
    int j = threadIdx.x;
    int start = blockIdx.x * 128;
    if (start >= N) return;
    int end = min(start + 128, N);
    int cur = gid[start];
    float x0 = 0.f, x1 = 0.f;
    for (int n = start; n < end; n++) {
        int g = gid[n];
        if (g != cur) {
            atomicAdd(&out[(size_t)cur * HD + 2 * j], x0);
            atomicAdd(&out[(size_t)cur * HD + 2 * j + 1], x1);
            cur = g; x0 = 0.f; x1 = 0.f;
        }
        u32 v = *(const u32*)&h[(size_t)n * HD + j * 2];
        x0 += bfLo(v); x1 += bfHi(v);
    }
    atomicAdd(&out[(size_t)cur * HD + 2 * j], x0);
    atomicAdd(&out[(size_t)cur * HD + 2 * j + 1], x1);
}

extern "C" void kernel_launch(void* const* d_in, const int* in_sizes, int n_in,
                              void* d_out, int out_size, void* d_ws, size_t ws_size,
                              hipStream_t stream) {
    (void)n_in; (void)ws_size;
    const float* x   = (const float*)d_in[0];
    const float* Wfc = (const float*)d_in[1];
    const float* bfc = (const float*)d_in[2];
    const float* W1  = (const float*)d_in[3];
    const float* b1  = (const float*)d_in[4];
    const float* W2  = (const float*)d_in[5];
    const float* b2  = (const float*)d_in[6];
    const int* src   = (const int*)d_in[7];
    const int* dst   = (const int*)d_in[8];
    const int* gid   = (const int*)d_in[9];

    int N = in_sizes[0] / DIN;       // 100000
    int E = in_sizes[7];             // 1600000
    int nTiles = (N + 127) / 128;
    int nB = (E + EB - 1) / EB;      // partition blocks (196)
    int nScan2 = NBKT * nB;          // histT length
    int nb2 = (nScan2 + 1023) / 1024;

    // workspace layout (~65 MB)
    u16* h = (u16*)d_ws;                          // N*128 bf16
    u16* z = h + (size_t)N * HD;                  // N*128 bf16
    int* off    = (int*)(z + (size_t)N * HD);     // N+1
    int* esrc   = off + (N + 1);                  // E
    int* bsums  = esrc + E;                       // 256
    int* bsums2 = bsums + 256;                    // 256
    int* boff   = bsums2 + 256;                   // NBKT+1 (+pad)
    int* histT  = boff + NBKT + 4;                // NBKT*nB
    u32* bpairs = (u32*)(histT + nScan2);         // E packed pairs

    int nScan = N + 1;
    int nb = (nScan + 1023) / 1024;

    // --- radix partition of edges by dst>>8 (no global atomics) ---
    rhist_kernel<<<nB, 256, 0, stream>>>(dst, histT, E, nB);
    scan1_kernel<<<nb2, 256, 0, stream>>>(histT, bsums2, nScan2);
    scan2_kernel<<<1, 1024, 0, stream>>>(bsums2, nb2);
    scan3_kernel<<<(nScan2 + 255) / 256, 256, 0, stream>>>(histT, bsums2, nScan2);
    boff_kernel<<<2, 256, 0, stream>>>(histT, boff, nB);
    rpos_kernel<<<nB, 256, 0, stream>>>(src, dst, histT, bpairs, E, nB);

    // --- per-node CSR offsets from partitioned pairs (LDS atomics only) ---
    bcount_kernel<<<NBKT, 256, 0, stream>>>(bpairs, boff, off, N);
    scan1_kernel<<<nb, 256, 0, stream>>>(off, bsums, nScan);
    scan2_kernel<<<1, 1024, 0, stream>>>(bsums, nb);
    scan3_kernel<<<(nScan + 255) / 256, 256, 0, stream>>>(off, bsums, nScan);
    bscatter_kernel<<<NBKT, 256, 0, stream>>>(bpairs, boff, off, esrc, N);

    // --- node projection (bf16 out) ---
    fc_kernel<<<512, 512, 0, stream>>>(x, Wfc, bfc, h, N, nTiles);

    // --- 3x GINConv (agg + fused MLP pair) ---
    for (int l = 0; l < 3; l++) {
        agg_kernel<<<(N + 3) / 4, 256, 0, stream>>>(h, off, esrc, z, N);
        mlp_pair_kernel<<<256, 512, 0, stream>>>(z, W1 + (size_t)l * HD * HD,
                                                 b1 + (size_t)l * HD,
                                                 W2 + (size_t)l * HD * HD,
                                                 b2 + (size_t)l * HD, h, N, nTiles);
    }

    // --- per-graph sum pooling ---
    zero_f32_kernel<<<(out_size + 255) / 256, 256, 0, stream>>>((float*)d_out, out_size);
    pool_kernel<<<(N + 127) / 128, 64, 0, stream>>>(h, gid, (float*)d_out, N);
}

// Round 7
// 456.269 us; speedup vs baseline: 3.9301x; 1.1040x over previous
//
#include <hip/hip_runtime.h>

#define DIN 55
#define HD 128
#define EB 8192          // edges per partition block
#define NBKT 512         // radix buckets (dst >> 8)

typedef unsigned short u16;
typedef unsigned int u32;
typedef short short8 __attribute__((ext_vector_type(8)));
typedef float f32x4 __attribute__((ext_vector_type(4)));

// ---- bf16 helpers ----
__device__ __forceinline__ u16 f2bf(float f) {
    u32 u = __float_as_uint(f);
    u32 r = (u + 0x7FFFu + ((u >> 16) & 1u)) >> 16;
    return (u16)r;
}
__device__ __forceinline__ float bfLo(u32 u) { return __uint_as_float(u << 16); }
__device__ __forceinline__ float bfHi(u32 u) { return __uint_as_float(u & 0xFFFF0000u); }

// ---------------- utility ----------------
__global__ void zero_f32_kernel(float* p, int n) {
    int i = blockIdx.x * blockDim.x + threadIdx.x;
    if (i < n) p[i] = 0.f;
}

// ---------------- hierarchical inclusive scan (for histT only) ----------------
__global__ __launch_bounds__(256) void scan1_kernel(int* data, int* bsums, int n) {
    __shared__ int sT[256];
    int t = threadIdx.x;
    int base = blockIdx.x * 1024 + t * 4;
    int v0 = (base + 0 < n) ? data[base + 0] : 0;
    int v1 = (base + 1 < n) ? data[base + 1] : 0;
    int v2 = (base + 2 < n) ? data[base + 2] : 0;
    int v3 = (base + 3 < n) ? data[base + 3] : 0;
    v1 += v0; v2 += v1; v3 += v2;
    sT[t] = v3;
    __syncthreads();
    for (int off = 1; off < 256; off <<= 1) {
        int x = (t >= off) ? sT[t - off] : 0;
        __syncthreads();
        sT[t] += x;
        __syncthreads();
    }
    int excl = (t == 0) ? 0 : sT[t - 1];
    if (base + 0 < n) data[base + 0] = v0 + excl;
    if (base + 1 < n) data[base + 1] = v1 + excl;
    if (base + 2 < n) data[base + 2] = v2 + excl;
    if (base + 3 < n) data[base + 3] = v3 + excl;
    if (t == 255) bsums[blockIdx.x] = sT[255];
}
__global__ __launch_bounds__(1024) void scan2_kernel(int* bsums, int nb) {
    __shared__ int s[1024];
    int t = threadIdx.x;
    int v = (t < nb) ? bsums[t] : 0;
    s[t] = v;
    __syncthreads();
    for (int o = 1; o < 1024; o <<= 1) {
        int x = (t >= o) ? s[t - o] : 0;
        __syncthreads();
        s[t] += x;
        __syncthreads();
    }
    if (t < nb) bsums[t] = s[t] - v;   // exclusive
}
__global__ void scan3_kernel(int* data, const int* __restrict__ bsums, int n) {
    int i = blockIdx.x * blockDim.x + threadIdx.x;
    if (i < n) data[i] += bsums[i >> 10];
}

// ---------------- radix partition of edges by dst>>8 ----------------
__global__ __launch_bounds__(256) void rhist_kernel(const int* __restrict__ dst,
                                                    int* __restrict__ histT, int E, int nB) {
    __shared__ int hh[NBKT];
    int t = threadIdx.x;
    for (int i = t; i < NBKT; i += 256) hh[i] = 0;
    __syncthreads();
    int base = blockIdx.x * EB;
    int end = min(base + EB, E);
    for (int i = base + t; i < end; i += 256) atomicAdd(&hh[dst[i] >> 8], 1);
    __syncthreads();
    for (int b = t; b < NBKT; b += 256) histT[b * nB + blockIdx.x] = hh[b];
}

__global__ void boff_kernel(const int* __restrict__ scanned, int* __restrict__ boff, int nB) {
    int b = blockIdx.x * blockDim.x + threadIdx.x;
    if (b == 0) boff[0] = 0;
    if (b < NBKT) boff[b + 1] = scanned[(b + 1) * nB - 1];
}

// ticket from scanned histT directly (exclusive base = scanned[flat-1]); LDS atomics only
__global__ __launch_bounds__(256) void rpos_kernel(const int* __restrict__ src,
                                                   const int* __restrict__ dst,
                                                   const int* __restrict__ scanned,
                                                   u32* __restrict__ bpairs, int E, int nB) {
    __shared__ int cur[NBKT];
    int t = threadIdx.x;
    for (int b = t; b < NBKT; b += 256) {
        int idx = b * nB + blockIdx.x;
        cur[b] = (idx == 0) ? 0 : scanned[idx - 1];
    }
    __syncthreads();
    int base = blockIdx.x * EB;
    int end = min(base + EB, E);
    for (int i = base + t; i < end; i += 256) {
        int d = dst[i];
        int p = atomicAdd(&cur[d >> 8], 1);
        bpairs[p] = ((u32)src[i] << 8) | (u32)(d & 255);
    }
}

// fused per-bucket: count -> local scan -> write off -> scatter esrc (all LDS)
__global__ __launch_bounds__(256) void bfinal_kernel(const u32* __restrict__ bpairs,
                                                     const int* __restrict__ boff,
                                                     int* __restrict__ off,
                                                     int* __restrict__ esrc, int N) {
    __shared__ int cnt[256];
    __shared__ int sc[256];
    __shared__ int cur[256];
    int b = blockIdx.x, t = threadIdx.x;
    cnt[t] = 0;
    __syncthreads();
    int lo = boff[b], hi = boff[b + 1];
    for (int i = lo + t; i < hi; i += 256) atomicAdd(&cnt[bpairs[i] & 255u], 1);
    __syncthreads();
    int v = cnt[t];
    sc[t] = v;
    __syncthreads();
    for (int o = 1; o < 256; o <<= 1) {
        int x = (t >= o) ? sc[t - o] : 0;
        __syncthreads();
        sc[t] += x;
        __syncthreads();
    }
    int incl = sc[t];
    int gbase = lo + incl - v;          // exclusive global base for node n
    int n = b * 256 + t;
    if (n < N) off[n] = gbase;
    if (n == N - 1) off[N] = lo + incl;
    cur[t] = gbase;
    __syncthreads();
    for (int i = lo + t; i < hi; i += 256) {
        u32 p = bpairs[i];
        int q = atomicAdd(&cur[p & 255u], 1);
        esrc[q] = (int)(p >> 8);
    }
}

// ---------------- node projection: h = x @ W_fc + b_fc  (fp32 math, bf16 out) ----------------
__global__ __launch_bounds__(512, 2) void fc_kernel(const float* __restrict__ x,
                                                    const float* __restrict__ Wfc,
                                                    const float* __restrict__ bfc,
                                                    u16* __restrict__ h,
                                                    int N, int nTiles) {
    __shared__ float sW[DIN * HD];
    __shared__ float sX[128 * 56];
    for (int i = threadIdx.x; i < DIN * HD / 4; i += 512)
        ((float4*)sW)[i] = ((const float4*)Wfc)[i];
    const int c = threadIdx.x & 15;
    const int r = threadIdx.x >> 4;
    float4 bb0 = ((const float4*)bfc)[2 * c];
    float4 bb1 = ((const float4*)bfc)[2 * c + 1];

    for (int tile = blockIdx.x; tile < nTiles; tile += gridDim.x) {
        int base = tile * 128;
        int limit = min(128, N - base) * DIN;
        __syncthreads();
        for (int i = threadIdx.x; i < 128 * DIN; i += 512) {
            float v = (i < limit) ? x[(size_t)base * DIN + i] : 0.f;
            sX[(i / DIN) * 56 + (i % DIN)] = v;
        }
        __syncthreads();

        float acc[4][8];
#pragma unroll
        for (int ii = 0; ii < 4; ii++) {
            acc[ii][0] = bb0.x; acc[ii][1] = bb0.y; acc[ii][2] = bb0.z; acc[ii][3] = bb0.w;
            acc[ii][4] = bb1.x; acc[ii][5] = bb1.y; acc[ii][6] = bb1.z; acc[ii][7] = bb1.w;
        }
        const int n0 = r * 4;
#pragma unroll 5
        for (int k = 0; k < DIN; k++) {
            float4 w0 = *(const float4*)&sW[k * HD + c * 8];
            float4 w1 = *(const float4*)&sW[k * HD + c * 8 + 4];
            float av[4] = {sX[(n0 + 0) * 56 + k], sX[(n0 + 1) * 56 + k],
                           sX[(n0 + 2) * 56 + k], sX[(n0 + 3) * 56 + k]};
#pragma unroll
            for (int ii = 0; ii < 4; ii++) {
                acc[ii][0] += av[ii] * w0.x; acc[ii][1] += av[ii] * w0.y;
                acc[ii][2] += av[ii] * w0.z; acc[ii][3] += av[ii] * w0.w;
                acc[ii][4] += av[ii] * w1.x; acc[ii][5] += av[ii] * w1.y;
                acc[ii][6] += av[ii] * w1.z; acc[ii][7] += av[ii] * w1.w;
            }
        }
        int nvalid = N - base;
#pragma unroll
        for (int ii = 0; ii < 4; ii++) {
            if (n0 + ii < nvalid) {
                u32 p0 = (u32)f2bf(acc[ii][0]) | ((u32)f2bf(acc[ii][1]) << 16);
                u32 p1 = (u32)f2bf(acc[ii][2]) | ((u32)f2bf(acc[ii][3]) << 16);
                u32 p2 = (u32)f2bf(acc[ii][4]) | ((u32)f2bf(acc[ii][5]) << 16);
                u32 p3 = (u32)f2bf(acc[ii][6]) | ((u32)f2bf(acc[ii][7]) << 16);
                *(uint4*)&h[(size_t)(base + n0 + ii) * HD + c * 8] = make_uint4(p0, p1, p2, p3);
            }
        }
    }
}

// ---------------- edge aggregation: z[n] = h[n] + sum_{e} h[esrc[e]]  (bf16) ----------------
__global__ __launch_bounds__(256) void agg_kernel(const u16* __restrict__ h,
                                                  const int* __restrict__ off,
                                                  const int* __restrict__ esrc,
                                                  u16* __restrict__ z, int N) {
    int w = threadIdx.x >> 6, lane = threadIdx.x & 63;
    int n = blockIdx.x * 4 + w;
    if (n >= N) return;
    int s0 = off[n], s1 = off[n + 1];
    int g = lane >> 4, q = lane & 15;
    float a0 = 0.f, a1 = 0.f, a2 = 0.f, a3 = 0.f, a4 = 0.f, a5 = 0.f, a6 = 0.f, a7 = 0.f;
    int t = s0;
#define ACC8(V) { a0 += bfLo(V.x); a1 += bfHi(V.x); a2 += bfLo(V.y); a3 += bfHi(V.y); \
                  a4 += bfLo(V.z); a5 += bfHi(V.z); a6 += bfLo(V.w); a7 += bfHi(V.w); }
    for (; t + 16 <= s1; t += 16) {
        int e0 = esrc[t + g], e1 = esrc[t + 4 + g];
        int e2 = esrc[t + 8 + g], e3 = esrc[t + 12 + g];
        uint4 v0 = *(const uint4*)&h[(size_t)e0 * HD + q * 8];
        uint4 v1 = *(const uint4*)&h[(size_t)e1 * HD + q * 8];
        uint4 v2 = *(const uint4*)&h[(size_t)e2 * HD + q * 8];
        uint4 v3 = *(const uint4*)&h[(size_t)e3 * HD + q * 8];
        ACC8(v0); ACC8(v1); ACC8(v2); ACC8(v3);
    }
    for (; t + 4 <= s1; t += 4) {
        int e0 = esrc[t + g];
        uint4 v0 = *(const uint4*)&h[(size_t)e0 * HD + q * 8];
        ACC8(v0);
    }
    if (t + g < s1) {
        int e0 = esrc[t + g];
        uint4 v0 = *(const uint4*)&h[(size_t)e0 * HD + q * 8];
        ACC8(v0);
    }
    if (g == 0) {
        uint4 sv = *(const uint4*)&h[(size_t)n * HD + q * 8];
        ACC8(sv);
    }
#undef ACC8
    a0 += __shfl_down(a0, 32); a1 += __shfl_down(a1, 32);
    a2 += __shfl_down(a2, 32); a3 += __shfl_down(a3, 32);
    a4 += __shfl_down(a4, 32); a5 += __shfl_down(a5, 32);
    a6 += __shfl_down(a6, 32); a7 += __shfl_down(a7, 32);
    a0 += __shfl_down(a0, 16); a1 += __shfl_down(a1, 16);
    a2 += __shfl_down(a2, 16); a3 += __shfl_down(a3, 16);
    a4 += __shfl_down(a4, 16); a5 += __shfl_down(a5, 16);
    a6 += __shfl_down(a6, 16); a7 += __shfl_down(a7, 16);
    if (g == 0) {
        u32 p0 = (u32)f2bf(a0) | ((u32)f2bf(a1) << 16);
        u32 p1 = (u32)f2bf(a2) | ((u32)f2bf(a3) << 16);
        u32 p2 = (u32)f2bf(a4) | ((u32)f2bf(a5) << 16);
        u32 p3 = (u32)f2bf(a6) | ((u32)f2bf(a7) << 16);
        *(uint4*)&z[(size_t)n * HD + q * 8] = make_uint4(p0, p1, p2, p3);
    }
}

// ---------------- fused MLP pair: out = relu(in@W1+b1)@W2+b2, in/out bf16 ----------------
// register-prefetch double buffer + coalesced epilogue through sZ
__global__ __launch_bounds__(512, 2) void mlp_pair_kernel(const u16* __restrict__ in,
                                                          const float* __restrict__ W1,
                                                          const float* __restrict__ b1,
                                                          const float* __restrict__ W2,
                                                          const float* __restrict__ b2,
                                                          u16* __restrict__ out,
                                                          int N, int nTiles) {
    __shared__ u16 sB1[16384];
    __shared__ u16 sB2[16384];
    __shared__ u16 sA[16384];
    __shared__ u16 sZ[128 * 136];

    const int t = threadIdx.x;
    for (int wsel = 0; wsel < 2; wsel++) {
        const float* W = wsel ? W2 : W1;
        u16* sB = wsel ? sB2 : sB1;
        __syncthreads();
        for (int c = t; c < 128 * 32; c += 512) {
            int k = c >> 5, j4 = c & 31;
            float4 wv = ((const float4*)W)[c];
            u32 p0 = (u32)f2bf(wv.x) | ((u32)f2bf(wv.y) << 16);
            u32 p1 = (u32)f2bf(wv.z) | ((u32)f2bf(wv.w) << 16);
            *(uint2*)&sZ[k * 136 + j4 * 4] = make_uint2(p0, p1);
        }
        __syncthreads();
        for (int e = t; e < 2048; e += 512) {
            int L = e & 63, gq = e >> 6;
            int ct = gq >> 2, kc = gq & 3;
            int j = ct * 16 + (L & 15);
            int k0 = kc * 32 + ((L >> 4) << 3);
            short8 sv;
#pragma unroll
            for (int i = 0; i < 8; i++) sv[i] = (short)sZ[(k0 + i) * 136 + j];
            int slot = L ^ (kc << 1);
            *(short8*)&sB[(((ct << 2) + kc) << 6 | slot) * 8] = sv;
        }
    }

    const int w = t >> 6, lane = t & 63;
    const int rbase = (w & 3) << 5;
    const int cbase = (w >> 2) << 6;
    float bias1[4], bias2[4];
#pragma unroll
    for (int ct = 0; ct < 4; ct++) {
        bias1[ct] = b1[cbase + ct * 16 + (lane & 15)];
        bias2[ct] = b2[cbase + ct * 16 + (lane & 15)];
    }

    // prefetch tile 0
    uint4 pf[4];
    int tile = blockIdx.x;
    if (tile < nTiles) {
        int base = tile * 128;
        int limit = min(128, N - base) * 16;
#pragma unroll
        for (int i = 0; i < 4; i++) {
            int c = t + 512 * i;
            uint4 raw = make_uint4(0, 0, 0, 0);
            if (c < limit)
                raw = *(const uint4*)&in[((size_t)(base + (c >> 4))) * HD + (c & 15) * 8];
            pf[i] = raw;
        }
    }

    for (; tile < nTiles; tile += gridDim.x) {
        int base = tile * 128;
        int nvalid = N - base;
        __syncthreads();                 // S1: prev tile fully done (sA & sZ free)
#pragma unroll
        for (int i = 0; i < 4; i++) {    // regs -> sA (swizzled fragment slots)
            int c = t + 512 * i;
            int n = c >> 4, k8 = c & 15;
            int rt = n >> 4, kc = k8 >> 2;
            int L = ((k8 & 3) << 4) | (n & 15);
            int slot = L ^ (kc << 1);
            *(uint4*)&sA[(((rt << 2) + kc) << 6 | slot) * 8] = pf[i];
        }
        __syncthreads();                 // S2

        // issue next tile's prefetch (overlaps with both GEMMs)
        int ntile = tile + gridDim.x;
        if (ntile < nTiles) {
            int nb2 = ntile * 128;
            int nlimit = min(128, N - nb2) * 16;
#pragma unroll
            for (int i = 0; i < 4; i++) {
                int c = t + 512 * i;
                uint4 raw = make_uint4(0, 0, 0, 0);
                if (c < nlimit)
                    raw = *(const uint4*)&in[((size_t)(nb2 + (c >> 4))) * HD + (c & 15) * 8];
                pf[i] = raw;
            }
        }

        // --- GEMM1 ---
        short8 af[2][4];
#pragma unroll
        for (int rt = 0; rt < 2; rt++) {
            int rtg = (rbase >> 4) + rt;
#pragma unroll
            for (int kc = 0; kc < 4; kc++)
                af[rt][kc] = *(const short8*)&sA[(((rtg << 2) + kc) << 6 | (lane ^ (kc << 1))) * 8];
        }
        f32x4 acc1[2][4];
#pragma unroll
        for (int rt = 0; rt < 2; rt++)
#pragma unroll
            for (int ct = 0; ct < 4; ct++) {
                acc1[rt][ct][0] = bias1[ct]; acc1[rt][ct][1] = bias1[ct];
                acc1[rt][ct][2] = bias1[ct]; acc1[rt][ct][3] = bias1[ct];
            }
#pragma unroll
        for (int ct = 0; ct < 4; ct++) {
            int ctg = (cbase >> 4) + ct;
#pragma unroll
            for (int kc = 0; kc < 4; kc++) {
                short8 bf = *(const short8*)&sB1[(((ctg << 2) + kc) << 6 | (lane ^ (kc << 1))) * 8];
                acc1[0][ct] = __builtin_amdgcn_mfma_f32_16x16x32_bf16(af[0][kc], bf, acc1[0][ct], 0, 0, 0);
                acc1[1][ct] = __builtin_amdgcn_mfma_f32_16x16x32_bf16(af[1][kc], bf, acc1[1][ct], 0, 0, 0);
            }
        }
        // --- transpose z1 = relu(acc1) into sZ ---
#pragma unroll
        for (int rt = 0; rt < 2; rt++) {
            int rowb = rbase + rt * 16 + ((lane >> 4) << 2);
#pragma unroll
            for (int ct = 0; ct < 4; ct++) {
                int col = cbase + ct * 16 + (lane & 15);
#pragma unroll
                for (int reg = 0; reg < 4; reg++)
                    sZ[(rowb + reg) * 136 + col] = f2bf(fmaxf(acc1[rt][ct][reg], 0.f));
            }
        }
        __syncthreads();                 // S3: z1 ready
        // --- GEMM2 ---
        short8 af2[2][4];
#pragma unroll
        for (int rt = 0; rt < 2; rt++) {
            int row = rbase + rt * 16 + (lane & 15);
#pragma unroll
            for (int kc = 0; kc < 4; kc++)
                af2[rt][kc] = *(const short8*)&sZ[row * 136 + kc * 32 + ((lane >> 4) << 3)];
        }
        f32x4 acc2[2][4];
#pragma unroll
        for (int rt = 0; rt < 2; rt++)
#pragma unroll
            for (int ct = 0; ct < 4; ct++) {
                acc2[rt][ct][0] = bias2[ct]; acc2[rt][ct][1] = bias2[ct];
                acc2[rt][ct][2] = bias2[ct]; acc2[rt][ct][3] = bias2[ct];
            }
#pragma unroll
        for (int ct = 0; ct < 4; ct++) {
            int ctg = (cbase >> 4) + ct;
#pragma unroll
            for (int kc = 0; kc < 4; kc++) {
                short8 bf = *(const short8*)&sB2[(((ctg << 2) + kc) << 6 | (lane ^ (kc << 1))) * 8];
                acc2[0][ct] = __builtin_amdgcn_mfma_f32_16x16x32_bf16(af2[0][kc], bf, acc2[0][ct], 0, 0, 0);
                acc2[1][ct] = __builtin_amdgcn_mfma_f32_16x16x32_bf16(af2[1][kc], bf, acc2[1][ct], 0, 0, 0);
            }
        }
        __syncthreads();                 // S4: af2 reads of sZ complete
        // --- stage acc2 -> sZ for coalesced store ---
#pragma unroll
        for (int rt = 0; rt < 2; rt++) {
            int rowb = rbase + rt * 16 + ((lane >> 4) << 2);
#pragma unroll
            for (int ct = 0; ct < 4; ct++) {
                int col = cbase + ct * 16 + (lane & 15);
#pragma unroll
                for (int reg = 0; reg < 4; reg++)
                    sZ[(rowb + reg) * 136 + col] = f2bf(acc2[rt][ct][reg]);
            }
        }
        __syncthreads();                 // S5
#pragma unroll
        for (int i = 0; i < 4; i++) {
            int c = t + 512 * i;
            int n = c >> 4, k8 = c & 15;
            if (n < nvalid)
                *(uint4*)&out[((size_t)(base + n)) * HD + k8 * 8] =
                    *(const uint4*)&sZ[n * 136 + k8 * 8];
        }
    }
}

// ---------------- per-graph sum pool (bf16 in, fp32 atomics out) ----------------
__global__ __launch_bounds__(64) void pool_kernel(const u16* __restrict__ h,
                                                  const int* __restrict__ gid,
                                                  float* __restrict__ out, int N) {
    const int CH = 32;
    int j = threadIdx.x;
    int start = blockIdx.x * CH;
    if (start >= N) return;
    int end = min(start + CH, N);
    int cur = gid[start];
    float x0 = 0.f, x1 = 0.f;
    for (int n = start; n < end; n++) {
        int g = gid[n];
        if (g != cur) {
            atomicAdd(&out[(size_t)cur * HD + 2 * j], x0);
            atomicAdd(&out[(size_t)cur * HD + 2 * j + 1], x1);
            cur = g; x0 = 0.f; x1 = 0.f;
        }
        u32 v = *(const u32*)&h[(size_t)n * HD + j * 2];
        x0 += bfLo(v); x1 += bfHi(v);
    }
    atomicAdd(&out[(size_t)cur * HD + 2 * j], x0);
    atomicAdd(&out[(size_t)cur * HD + 2 * j + 1], x1);
}

extern "C" void kernel_launch(void* const* d_in, const int* in_sizes, int n_in,
                              void* d_out, int out_size, void* d_ws, size_t ws_size,
                              hipStream_t stream) {
    (void)n_in; (void)ws_size;
    const float* x   = (const float*)d_in[0];
    const float* Wfc = (const float*)d_in[1];
    const float* bfc = (const float*)d_in[2];
    const float* W1  = (const float*)d_in[3];
    const float* b1  = (const float*)d_in[4];
    const float* W2  = (const float*)d_in[5];
    const float* b2  = (const float*)d_in[6];
    const int* src   = (const int*)d_in[7];
    const int* dst   = (const int*)d_in[8];
    const int* gid   = (const int*)d_in[9];

    int N = in_sizes[0] / DIN;       // 100000
    int E = in_sizes[7];             // 1600000
    int nTiles = (N + 127) / 128;
    int nB = (E + EB - 1) / EB;      // partition blocks (196)
    int nScan2 = NBKT * nB;          // histT length
    int nb2 = (nScan2 + 1023) / 1024;

    // workspace layout (~65 MB)
    u16* h = (u16*)d_ws;                          // N*128 bf16
    u16* z = h + (size_t)N * HD;                  // N*128 bf16
    int* off    = (int*)(z + (size_t)N * HD);     // N+1
    int* esrc   = off + (N + 1);                  // E
    int* bsums2 = esrc + E;                       // 256
    int* boff   = bsums2 + 256;                   // NBKT+1 (+pad)
    int* histT  = boff + NBKT + 4;                // NBKT*nB (odd total ints ok: u32 align)
    u32* bpairs = (u32*)(histT + nScan2);         // E packed pairs

    // --- radix partition of edges by dst>>8 (no global atomics) ---
    rhist_kernel<<<nB, 256, 0, stream>>>(dst, histT, E, nB);
    scan1_kernel<<<nb2, 256, 0, stream>>>(histT, bsums2, nScan2);
    scan2_kernel<<<1, 1024, 0, stream>>>(bsums2, nb2);
    scan3_kernel<<<(nScan2 + 255) / 256, 256, 0, stream>>>(histT, bsums2, nScan2);
    boff_kernel<<<2, 256, 0, stream>>>(histT, boff, nB);
    rpos_kernel<<<nB, 256, 0, stream>>>(src, dst, histT, bpairs, E, nB);

    // --- fused per-node CSR offsets + scatter (per-bucket, LDS only) ---
    bfinal_kernel<<<NBKT, 256, 0, stream>>>(bpairs, boff, off, esrc, N);

    // --- node projection (bf16 out) ---
    fc_kernel<<<512, 512, 0, stream>>>(x, Wfc, bfc, h, N, nTiles);

    // --- 3x GINConv (agg + fused MLP pair) ---
    for (int l = 0; l < 3; l++) {
        agg_kernel<<<(N + 3) / 4, 256, 0, stream>>>(h, off, esrc, z, N);
        mlp_pair_kernel<<<256, 512, 0, stream>>>(z, W1 + (size_t)l * HD * HD,
                                                 b1 + (size_t)l * HD,
                                                 W2 + (size_t)l * HD * HD,
                                                 b2 + (size_t)l * HD, h, N, nTiles);
    }

    // --- per-graph sum pooling ---
    zero_f32_kernel<<<(out_size + 255) / 256, 256, 0, stream>>>((float*)d_out, out_size);
    pool_kernel<<<(N + 31) / 32, 64, 0, stream>>>(h, gid, (float*)d_out, N);
}

// Round 8
// 456.225 us; speedup vs baseline: 3.9305x; 1.0001x over previous
//
#include <hip/hip_runtime.h>

#define DIN 55
#define HD 128
#define EB 8192          // edges per partition block
#define NBKT 512         // radix buckets (dst >> 8)

typedef unsigned short u16;
typedef unsigned int u32;
typedef short short8 __attribute__((ext_vector_type(8)));
typedef float f32x4 __attribute__((ext_vector_type(4)));

// ---- bf16 helpers ----
__device__ __forceinline__ u16 f2bf(float f) {
    u32 u = __float_as_uint(f);
    u32 r = (u + 0x7FFFu + ((u >> 16) & 1u)) >> 16;
    return (u16)r;
}
__device__ __forceinline__ float bfLo(u32 u) { return __uint_as_float(u << 16); }
__device__ __forceinline__ float bfHi(u32 u) { return __uint_as_float(u & 0xFFFF0000u); }

// ---------------- utility ----------------
__global__ void zero_f32_kernel(float* p, int n) {
    int i = blockIdx.x * blockDim.x + threadIdx.x;
    if (i < n) p[i] = 0.f;
}

// ---------------- hierarchical inclusive scan (for histT only) ----------------
__global__ __launch_bounds__(256) void scan1_kernel(int* data, int* bsums, int n) {
    __shared__ int sT[256];
    int t = threadIdx.x;
    int base = blockIdx.x * 1024 + t * 4;
    int v0 = (base + 0 < n) ? data[base + 0] : 0;
    int v1 = (base + 1 < n) ? data[base + 1] : 0;
    int v2 = (base + 2 < n) ? data[base + 2] : 0;
    int v3 = (base + 3 < n) ? data[base + 3] : 0;
    v1 += v0; v2 += v1; v3 += v2;
    sT[t] = v3;
    __syncthreads();
    for (int off = 1; off < 256; off <<= 1) {
        int x = (t >= off) ? sT[t - off] : 0;
        __syncthreads();
        sT[t] += x;
        __syncthreads();
    }
    int excl = (t == 0) ? 0 : sT[t - 1];
    if (base + 0 < n) data[base + 0] = v0 + excl;
    if (base + 1 < n) data[base + 1] = v1 + excl;
    if (base + 2 < n) data[base + 2] = v2 + excl;
    if (base + 3 < n) data[base + 3] = v3 + excl;
    if (t == 255) bsums[blockIdx.x] = sT[255];
}
__global__ __launch_bounds__(1024) void scan2_kernel(int* bsums, int nb) {
    __shared__ int s[1024];
    int t = threadIdx.x;
    int v = (t < nb) ? bsums[t] : 0;
    s[t] = v;
    __syncthreads();
    for (int o = 1; o < 1024; o <<= 1) {
        int x = (t >= o) ? s[t - o] : 0;
        __syncthreads();
        s[t] += x;
        __syncthreads();
    }
    if (t < nb) bsums[t] = s[t] - v;   // exclusive
}
__global__ void scan3_kernel(int* data, const int* __restrict__ bsums, int n) {
    int i = blockIdx.x * blockDim.x + threadIdx.x;
    if (i < n) data[i] += bsums[i >> 10];
}

// ---------------- radix partition of edges by dst>>8 ----------------
__global__ __launch_bounds__(256) void rhist_kernel(const int* __restrict__ dst,
                                                    int* __restrict__ histT, int E, int nB) {
    __shared__ int hh[NBKT];
    int t = threadIdx.x;
    for (int i = t; i < NBKT; i += 256) hh[i] = 0;
    __syncthreads();
    int base = blockIdx.x * EB;
    int end = min(base + EB, E);
    for (int i = base + t; i < end; i += 256) atomicAdd(&hh[dst[i] >> 8], 1);
    __syncthreads();
    for (int b = t; b < NBKT; b += 256) histT[b * nB + blockIdx.x] = hh[b];
}

__global__ void boff_kernel(const int* __restrict__ scanned, int* __restrict__ boff, int nB) {
    int b = blockIdx.x * blockDim.x + threadIdx.x;
    if (b == 0) boff[0] = 0;
    if (b < NBKT) boff[b + 1] = scanned[(b + 1) * nB - 1];
}

// ticket from scanned histT directly (exclusive base = scanned[flat-1]); LDS atomics only
__global__ __launch_bounds__(256) void rpos_kernel(const int* __restrict__ src,
                                                   const int* __restrict__ dst,
                                                   const int* __restrict__ scanned,
                                                   u32* __restrict__ bpairs, int E, int nB) {
    __shared__ int cur[NBKT];
    int t = threadIdx.x;
    for (int b = t; b < NBKT; b += 256) {
        int idx = b * nB + blockIdx.x;
        cur[b] = (idx == 0) ? 0 : scanned[idx - 1];
    }
    __syncthreads();
    int base = blockIdx.x * EB;
    int end = min(base + EB, E);
    for (int i = base + t; i < end; i += 256) {
        int d = dst[i];
        int p = atomicAdd(&cur[d >> 8], 1);
        bpairs[p] = ((u32)src[i] << 8) | (u32)(d & 255);
    }
}

// fused per-bucket: count -> local scan -> write off -> scatter esrc (all LDS)
__global__ __launch_bounds__(256) void bfinal_kernel(const u32* __restrict__ bpairs,
                                                     const int* __restrict__ boff,
                                                     int* __restrict__ off,
                                                     int* __restrict__ esrc, int N) {
    __shared__ int cnt[256];
    __shared__ int sc[256];
    __shared__ int cur[256];
    int b = blockIdx.x, t = threadIdx.x;
    cnt[t] = 0;
    __syncthreads();
    int lo = boff[b], hi = boff[b + 1];
    for (int i = lo + t; i < hi; i += 256) atomicAdd(&cnt[bpairs[i] & 255u], 1);
    __syncthreads();
    int v = cnt[t];
    sc[t] = v;
    __syncthreads();
    for (int o = 1; o < 256; o <<= 1) {
        int x = (t >= o) ? sc[t - o] : 0;
        __syncthreads();
        sc[t] += x;
        __syncthreads();
    }
    int incl = sc[t];
    int gbase = lo + incl - v;          // exclusive global base for node n
    int n = b * 256 + t;
    if (n < N) off[n] = gbase;
    if (n == N - 1) off[N] = lo + incl;
    cur[t] = gbase;
    __syncthreads();
    for (int i = lo + t; i < hi; i += 256) {
        u32 p = bpairs[i];
        int q = atomicAdd(&cur[p & 255u], 1);
        esrc[q] = (int)(p >> 8);
    }
}

// ---------------- node projection: h = x @ W_fc + b_fc  (fp32 math, bf16 out) ----------------
__global__ __launch_bounds__(512, 2) void fc_kernel(const float* __restrict__ x,
                                                    const float* __restrict__ Wfc,
                                                    const float* __restrict__ bfc,
                                                    u16* __restrict__ h,
                                                    int N, int nTiles) {
    __shared__ float sW[DIN * HD];
    __shared__ float sX[128 * 56];
    for (int i = threadIdx.x; i < DIN * HD / 4; i += 512)
        ((float4*)sW)[i] = ((const float4*)Wfc)[i];
    const int c = threadIdx.x & 15;
    const int r = threadIdx.x >> 4;
    float4 bb0 = ((const float4*)bfc)[2 * c];
    float4 bb1 = ((const float4*)bfc)[2 * c + 1];

    for (int tile = blockIdx.x; tile < nTiles; tile += gridDim.x) {
        int base = tile * 128;
        int limit = min(128, N - base) * DIN;
        __syncthreads();
        for (int i = threadIdx.x; i < 128 * DIN; i += 512) {
            float v = (i < limit) ? x[(size_t)base * DIN + i] : 0.f;
            sX[(i / DIN) * 56 + (i % DIN)] = v;
        }
        __syncthreads();

        float acc[4][8];
#pragma unroll
        for (int ii = 0; ii < 4; ii++) {
            acc[ii][0] = bb0.x; acc[ii][1] = bb0.y; acc[ii][2] = bb0.z; acc[ii][3] = bb0.w;
            acc[ii][4] = bb1.x; acc[ii][5] = bb1.y; acc[ii][6] = bb1.z; acc[ii][7] = bb1.w;
        }
        const int n0 = r * 4;
#pragma unroll 5
        for (int k = 0; k < DIN; k++) {
            float4 w0 = *(const float4*)&sW[k * HD + c * 8];
            float4 w1 = *(const float4*)&sW[k * HD + c * 8 + 4];
            float av[4] = {sX[(n0 + 0) * 56 + k], sX[(n0 + 1) * 56 + k],
                           sX[(n0 + 2) * 56 + k], sX[(n0 + 3) * 56 + k]};
#pragma unroll
            for (int ii = 0; ii < 4; ii++) {
                acc[ii][0] += av[ii] * w0.x; acc[ii][1] += av[ii] * w0.y;
                acc[ii][2] += av[ii] * w0.z; acc[ii][3] += av[ii] * w0.w;
                acc[ii][4] += av[ii] * w1.x; acc[ii][5] += av[ii] * w1.y;
                acc[ii][6] += av[ii] * w1.z; acc[ii][7] += av[ii] * w1.w;
            }
        }
        int nvalid = N - base;
#pragma unroll
        for (int ii = 0; ii < 4; ii++) {
            if (n0 + ii < nvalid) {
                u32 p0 = (u32)f2bf(acc[ii][0]) | ((u32)f2bf(acc[ii][1]) << 16);
                u32 p1 = (u32)f2bf(acc[ii][2]) | ((u32)f2bf(acc[ii][3]) << 16);
                u32 p2 = (u32)f2bf(acc[ii][4]) | ((u32)f2bf(acc[ii][5]) << 16);
                u32 p3 = (u32)f2bf(acc[ii][6]) | ((u32)f2bf(acc[ii][7]) << 16);
                *(uint4*)&h[(size_t)(base + n0 + ii) * HD + c * 8] = make_uint4(p0, p1, p2, p3);
            }
        }
    }
}

// ---------------- edge aggregation: z[n] = h[n] + sum_{e} h[esrc[e]]  (bf16) ----------------
__global__ __launch_bounds__(256) void agg_kernel(const u16* __restrict__ h,
                                                  const int* __restrict__ off,
                                                  const int* __restrict__ esrc,
                                                  u16* __restrict__ z, int N) {
    int w = threadIdx.x >> 6, lane = threadIdx.x & 63;
    int n = blockIdx.x * 4 + w;
    if (n >= N) return;
    int s0 = off[n], s1 = off[n + 1];
    int g = lane >> 4, q = lane & 15;
    float a0 = 0.f, a1 = 0.f, a2 = 0.f, a3 = 0.f, a4 = 0.f, a5 = 0.f, a6 = 0.f, a7 = 0.f;
    int t = s0;
#define ACC8(V) { a0 += bfLo(V.x); a1 += bfHi(V.x); a2 += bfLo(V.y); a3 += bfHi(V.y); \
                  a4 += bfLo(V.z); a5 += bfHi(V.z); a6 += bfLo(V.w); a7 += bfHi(V.w); }
    for (; t + 16 <= s1; t += 16) {
        int e0 = esrc[t + g], e1 = esrc[t + 4 + g];
        int e2 = esrc[t + 8 + g], e3 = esrc[t + 12 + g];
        uint4 v0 = *(const uint4*)&h[(size_t)e0 * HD + q * 8];
        uint4 v1 = *(const uint4*)&h[(size_t)e1 * HD + q * 8];
        uint4 v2 = *(const uint4*)&h[(size_t)e2 * HD + q * 8];
        uint4 v3 = *(const uint4*)&h[(size_t)e3 * HD + q * 8];
        ACC8(v0); ACC8(v1); ACC8(v2); ACC8(v3);
    }
    for (; t + 4 <= s1; t += 4) {
        int e0 = esrc[t + g];
        uint4 v0 = *(const uint4*)&h[(size_t)e0 * HD + q * 8];
        ACC8(v0);
    }
    if (t + g < s1) {
        int e0 = esrc[t + g];
        uint4 v0 = *(const uint4*)&h[(size_t)e0 * HD + q * 8];
        ACC8(v0);
    }
    if (g == 0) {
        uint4 sv = *(const uint4*)&h[(size_t)n * HD + q * 8];
        ACC8(sv);
    }
#undef ACC8
    a0 += __shfl_down(a0, 32); a1 += __shfl_down(a1, 32);
    a2 += __shfl_down(a2, 32); a3 += __shfl_down(a3, 32);
    a4 += __shfl_down(a4, 32); a5 += __shfl_down(a5, 32);
    a6 += __shfl_down(a6, 32); a7 += __shfl_down(a7, 32);
    a0 += __shfl_down(a0, 16); a1 += __shfl_down(a1, 16);
    a2 += __shfl_down(a2, 16); a3 += __shfl_down(a3, 16);
    a4 += __shfl_down(a4, 16); a5 += __shfl_down(a5, 16);
    a6 += __shfl_down(a6, 16); a7 += __shfl_down(a7, 16);
    if (g == 0) {
        u32 p0 = (u32)f2bf(a0) | ((u32)f2bf(a1) << 16);
        u32 p1 = (u32)f2bf(a2) | ((u32)f2bf(a3) << 16);
        u32 p2 = (u32)f2bf(a4) | ((u32)f2bf(a5) << 16);
        u32 p3 = (u32)f2bf(a6) | ((u32)f2bf(a7) << 16);
        *(uint4*)&z[(size_t)n * HD + q * 8] = make_uint4(p0, p1, p2, p3);
    }
}

// ---------------- fused MLP pair (swapped operands): out = relu(in@W1+b1)@W2+b2 ----------------
// Both GEMMs computed transposed: D[feature][node] with A = weight frags, B = activation frags.
// C/D layout => lane's 4 regs are 4 consecutive FEATURES of one node -> b64 row-major LDS writes,
// GEMM2 B-frags are contiguous b128 reads. No scalar transposes.
__global__ __launch_bounds__(512, 2) void mlp_pair_kernel(const u16* __restrict__ in,
                                                          const float* __restrict__ W1,
                                                          const float* __restrict__ b1,
                                                          const float* __restrict__ W2,
                                                          const float* __restrict__ b2,
                                                          u16* __restrict__ out,
                                                          int N, int nTiles) {
    __shared__ u16 sB1[16384];           // W1 frags: [ft][kc][slot][8], lane holds W1[k0..k0+7][j]
    __shared__ u16 sB2[16384];           // W2 frags
    __shared__ u16 sA[16384];            // activation frags: [nt][kc][slot][8]
    __shared__ u16 sZ[128 * 136];        // row-major activations [node][feature], pad 136

    const int t = threadIdx.x;
    // --- build weight frags (stage fp32->bf16 rows into sZ scratch, then fragment) ---
    for (int wsel = 0; wsel < 2; wsel++) {
        const float* W = wsel ? W2 : W1;
        u16* sB = wsel ? sB2 : sB1;
        __syncthreads();
        for (int c = t; c < 128 * 32; c += 512) {
            int k = c >> 5, j4 = c & 31;
            float4 wv = ((const float4*)W)[c];
            u32 p0 = (u32)f2bf(wv.x) | ((u32)f2bf(wv.y) << 16);
            u32 p1 = (u32)f2bf(wv.z) | ((u32)f2bf(wv.w) << 16);
            *(uint2*)&sZ[k * 136 + j4 * 4] = make_uint2(p0, p1);
        }
        __syncthreads();
        for (int e = t; e < 2048; e += 512) {
            int L = e & 63, gq = e >> 6;
            int ct = gq >> 2, kc = gq & 3;
            int j = ct * 16 + (L & 15);
            int k0 = kc * 32 + ((L >> 4) << 3);
            short8 sv;
#pragma unroll
            for (int i = 0; i < 8; i++) sv[i] = (short)sZ[(k0 + i) * 136 + j];
            int slot = L ^ (kc << 1);
            *(short8*)&sB[(((ct << 2) + kc) << 6 | slot) * 8] = sv;
        }
    }

    const int w = t >> 6, lane = t & 63;
    const int col = lane & 15;           // node within tile
    const int fq = lane >> 4;            // feature quad
    const int fbase = (w & 3) << 5;      // wave's 32 features (2 f-tiles)
    const int nbase = (w >> 2) << 6;     // wave's 64 nodes (4 n-tiles)
    float4 bias1v[2], bias2v[2];
#pragma unroll
    for (int ftl = 0; ftl < 2; ftl++) {
        bias1v[ftl] = *(const float4*)&b1[fbase + ftl * 16 + fq * 4];
        bias2v[ftl] = *(const float4*)&b2[fbase + ftl * 16 + fq * 4];
    }

    // prefetch tile 0
    uint4 pf[4];
    int tile = blockIdx.x;
    if (tile < nTiles) {
        int base = tile * 128;
        int limit = min(128, N - base) * 16;
#pragma unroll
        for (int i = 0; i < 4; i++) {
            int c = t + 512 * i;
            uint4 raw = make_uint4(0, 0, 0, 0);
            if (c < limit)
                raw = *(const uint4*)&in[((size_t)(base + (c >> 4))) * HD + (c & 15) * 8];
            pf[i] = raw;
        }
    }

    for (; tile < nTiles; tile += gridDim.x) {
        int base = tile * 128;
        int nvalid = N - base;
        __syncthreads();                 // S1: prev tile fully done (sA & sZ free)
#pragma unroll
        for (int i = 0; i < 4; i++) {    // regs -> sA (swizzled fragment slots)
            int c = t + 512 * i;
            int n = c >> 4, k8 = c & 15;
            int nt = n >> 4, kc = k8 >> 2;
            int L = ((k8 & 3) << 4) | (n & 15);
            int slot = L ^ (kc << 1);
            *(uint4*)&sA[(((nt << 2) + kc) << 6 | slot) * 8] = pf[i];
        }
        __syncthreads();                 // S2

        // issue next tile's prefetch (overlaps with both GEMMs)
        int ntile = tile + gridDim.x;
        if (ntile < nTiles) {
            int nb2 = ntile * 128;
            int nlimit = min(128, N - nb2) * 16;
#pragma unroll
            for (int i = 0; i < 4; i++) {
                int c = t + 512 * i;
                uint4 raw = make_uint4(0, 0, 0, 0);
                if (c < nlimit)
                    raw = *(const uint4*)&in[((size_t)(nb2 + (c >> 4))) * HD + (c & 15) * 8];
                pf[i] = raw;
            }
        }

        // --- GEMM1: D[feature][node] = W1^T (A) x in^T (B) ---
        short8 aw1[2][4];
#pragma unroll
        for (int ftl = 0; ftl < 2; ftl++) {
            int ft = ((w & 3) << 1) + ftl;
#pragma unroll
            for (int kc = 0; kc < 4; kc++)
                aw1[ftl][kc] = *(const short8*)&sB1[(((ft << 2) + kc) << 6 | (lane ^ (kc << 1))) * 8];
        }
        short8 bx[4][4];
#pragma unroll
        for (int ntl = 0; ntl < 4; ntl++) {
            int nt = ((w >> 2) << 2) + ntl;
#pragma unroll
            for (int kc = 0; kc < 4; kc++)
                bx[ntl][kc] = *(const short8*)&sA[(((nt << 2) + kc) << 6 | (lane ^ (kc << 1))) * 8];
        }
        f32x4 acc1[2][4];
#pragma unroll
        for (int ftl = 0; ftl < 2; ftl++)
#pragma unroll
            for (int ntl = 0; ntl < 4; ntl++) {
                acc1[ftl][ntl][0] = bias1v[ftl].x; acc1[ftl][ntl][1] = bias1v[ftl].y;
                acc1[ftl][ntl][2] = bias1v[ftl].z; acc1[ftl][ntl][3] = bias1v[ftl].w;
            }
#pragma unroll
        for (int ntl = 0; ntl < 4; ntl++)
#pragma unroll
            for (int kc = 0; kc < 4; kc++) {
                acc1[0][ntl] = __builtin_amdgcn_mfma_f32_16x16x32_bf16(aw1[0][kc], bx[ntl][kc], acc1[0][ntl], 0, 0, 0);
                acc1[1][ntl] = __builtin_amdgcn_mfma_f32_16x16x32_bf16(aw1[1][kc], bx[ntl][kc], acc1[1][ntl], 0, 0, 0);
            }
        // --- write z1 = relu(acc1) row-major into sZ via b64 (4 consecutive features) ---
#pragma unroll
        for (int ftl = 0; ftl < 2; ftl++) {
            int f = fbase + ftl * 16 + fq * 4;
#pragma unroll
            for (int ntl = 0; ntl < 4; ntl++) {
                int n = nbase + ntl * 16 + col;
                float v0 = fmaxf(acc1[ftl][ntl][0], 0.f);
                float v1 = fmaxf(acc1[ftl][ntl][1], 0.f);
                float v2 = fmaxf(acc1[ftl][ntl][2], 0.f);
                float v3 = fmaxf(acc1[ftl][ntl][3], 0.f);
                u32 lo = (u32)f2bf(v0) | ((u32)f2bf(v1) << 16);
                u32 hi = (u32)f2bf(v2) | ((u32)f2bf(v3) << 16);
                *(uint2*)&sZ[n * 136 + f] = make_uint2(lo, hi);
            }
        }
        __syncthreads();                 // S3: z1 ready
        // --- GEMM2: D[feature][node] = W2^T (A) x z1^T (B); B-frags contiguous b128 ---
        short8 aw2[2][4];
#pragma unroll
        for (int ftl = 0; ftl < 2; ftl++) {
            int ft = ((w & 3) << 1) + ftl;
#pragma unroll
            for (int kc = 0; kc < 4; kc++)
                aw2[ftl][kc] = *(const short8*)&sB2[(((ft << 2) + kc) << 6 | (lane ^ (kc << 1))) * 8];
        }
        short8 bz[4][4];
#pragma unroll
        for (int ntl = 0; ntl < 4; ntl++) {
            int n = nbase + ntl * 16 + col;
#pragma unroll
            for (int kc = 0; kc < 4; kc++) {
                int k0 = kc * 32 + fq * 8;
                bz[ntl][kc] = *(const short8*)&sZ[n * 136 + k0];
            }
        }
        f32x4 acc2[2][4];
#pragma unroll
        for (int ftl = 0; ftl < 2; ftl++)
#pragma unroll
            for (int ntl = 0; ntl < 4; ntl++) {
                acc2[ftl][ntl][0] = bias2v[ftl].x; acc2[ftl][ntl][1] = bias2v[ftl].y;
                acc2[ftl][ntl][2] = bias2v[ftl].z; acc2[ftl][ntl][3] = bias2v[ftl].w;
            }
#pragma unroll
        for (int ntl = 0; ntl < 4; ntl++)
#pragma unroll
            for (int kc = 0; kc < 4; kc++) {
                acc2[0][ntl] = __builtin_amdgcn_mfma_f32_16x16x32_bf16(aw2[0][kc], bz[ntl][kc], acc2[0][ntl], 0, 0, 0);
                acc2[1][ntl] = __builtin_amdgcn_mfma_f32_16x16x32_bf16(aw2[1][kc], bz[ntl][kc], acc2[1][ntl], 0, 0, 0);
            }
        __syncthreads();                 // S4: all sZ reads complete
        // --- stage acc2 -> sZ row-major via b64 ---
#pragma unroll
        for (int ftl = 0; ftl < 2; ftl++) {
            int f = fbase + ftl * 16 + fq * 4;
#pragma unroll
            for (int ntl = 0; ntl < 4; ntl++) {
                int n = nbase + ntl * 16 + col;
                u32 lo = (u32)f2bf(acc2[ftl][ntl][0]) | ((u32)f2bf(acc2[ftl][ntl][1]) << 16);
                u32 hi = (u32)f2bf(acc2[ftl][ntl][2]) | ((u32)f2bf(acc2[ftl][ntl][3]) << 16);
                *(uint2*)&sZ[n * 136 + f] = make_uint2(lo, hi);
            }
        }
        __syncthreads();                 // S5
#pragma unroll
        for (int i = 0; i < 4; i++) {
            int c = t + 512 * i;
            int n = c >> 4, k8 = c & 15;
            if (n < nvalid)
                *(uint4*)&out[((size_t)(base + n)) * HD + k8 * 8] =
                    *(const uint4*)&sZ[n * 136 + k8 * 8];
        }
    }
}

// ---------------- per-graph sum pool (bf16 in, fp32 atomics out) ----------------
__global__ __launch_bounds__(64) void pool_kernel(const u16* __restrict__ h,
                                                  const int* __restrict__ gid,
                                                  float* __restrict__ out, int N) {
    const int CH = 32;
    int j = threadIdx.x;
    int start = blockIdx.x * CH;
    if (start >= N) return;
    int end = min(start + CH, N);
    int cur = gid[start];
    float x0 = 0.f, x1 = 0.f;
    for (int n = start; n < end; n++) {
        int g = gid[n];
        if (g != cur) {
            atomicAdd(&out[(size_t)cur * HD + 2 * j], x0);
            atomicAdd(&out[(size_t)cur * HD + 2 * j + 1], x1);
            cur = g; x0 = 0.f; x1 = 0.f;
        }
        u32 v = *(const u32*)&h[(size_t)n * HD + j * 2];
        x0 += bfLo(v); x1 += bfHi(v);
    }
    atomicAdd(&out[(size_t)cur * HD + 2 * j], x0);
    atomicAdd(&out[(size_t)cur * HD + 2 * j + 1], x1);
}

extern "C" void kernel_launch(void* const* d_in, const int* in_sizes, int n_in,
                              void* d_out, int out_size, void* d_ws, size_t ws_size,
                              hipStream_t stream) {
    (void)n_in; (void)ws_size;
    const float* x   = (const float*)d_in[0];
    const float* Wfc = (const float*)d_in[1];
    const float* bfc = (const float*)d_in[2];
    const float* W1  = (const float*)d_in[3];
    const float* b1  = (const float*)d_in[4];
    const float* W2  = (const float*)d_in[5];
    const float* b2  = (const float*)d_in[6];
    const int* src   = (const int*)d_in[7];
    const int* dst   = (const int*)d_in[8];
    const int* gid   = (const int*)d_in[9];

    int N = in_sizes[0] / DIN;       // 100000
    int E = in_sizes[7];             // 1600000
    int nTiles = (N + 127) / 128;
    int nB = (E + EB - 1) / EB;      // partition blocks (196)
    int nScan2 = NBKT * nB;          // histT length
    int nb2 = (nScan2 + 1023) / 1024;

    // workspace layout (~65 MB)
    u16* h = (u16*)d_ws;                          // N*128 bf16
    u16* z = h + (size_t)N * HD;                  // N*128 bf16
    int* off    = (int*)(z + (size_t)N * HD);     // N+1
    int* esrc   = off + (N + 1);                  // E
    int* bsums2 = esrc + E;                       // 256
    int* boff   = bsums2 + 256;                   // NBKT+1 (+pad)
    int* histT  = boff + NBKT + 4;                // NBKT*nB
    u32* bpairs = (u32*)(histT + nScan2);         // E packed pairs

    // --- radix partition of edges by dst>>8 (no global atomics) ---
    rhist_kernel<<<nB, 256, 0, stream>>>(dst, histT, E, nB);
    scan1_kernel<<<nb2, 256, 0, stream>>>(histT, bsums2, nScan2);
    scan2_kernel<<<1, 1024, 0, stream>>>(bsums2, nb2);
    scan3_kernel<<<(nScan2 + 255) / 256, 256, 0, stream>>>(histT, bsums2, nScan2);
    boff_kernel<<<2, 256, 0, stream>>>(histT, boff, nB);
    rpos_kernel<<<nB, 256, 0, stream>>>(src, dst, histT, bpairs, E, nB);

    // --- fused per-node CSR offsets + scatter (per-bucket, LDS only) ---
    bfinal_kernel<<<NBKT, 256, 0, stream>>>(bpairs, boff, off, esrc, N);

    // --- node projection (bf16 out) ---
    fc_kernel<<<512, 512, 0, stream>>>(x, Wfc, bfc, h, N, nTiles);

    // --- 3x GINConv (agg + fused MLP pair) ---
    for (int l = 0; l < 3; l++) {
        agg_kernel<<<(N + 3) / 4, 256, 0, stream>>>(h, off, esrc, z, N);
        mlp_pair_kernel<<<256, 512, 0, stream>>>(z, W1 + (size_t)l * HD * HD,
                                                 b1 + (size_t)l * HD,
                                                 W2 + (size_t)l * HD * HD,
                                                 b2 + (size_t)l * HD, h, N, nTiles);
    }

    // --- per-graph sum pooling ---
    zero_f32_kernel<<<(out_size + 255) / 256, 256, 0, stream>>>((float*)d_out, out_size);
    pool_kernel<<<(N + 31) / 32, 64, 0, stream>>>(h, gid, (float*)d_out, N);
}